// Round 3
// baseline (406.918 us; speedup 1.0000x reference)
//
#include <hip/hip_runtime.h>
#include <stdint.h>

#define B_SZ    2
#define L_SEQ   2048
#define DMODEL  768
#define DSTATE  16
#define DINNER  1536
#define DTRANK  48
#define M_ROWS  4096      // B*L
#define NCHUNK  32

typedef __attribute__((ext_vector_type(8))) short bf16x8;
typedef __attribute__((ext_vector_type(4))) float f32x4;
typedef __attribute__((ext_vector_type(4))) unsigned int u32x4;
typedef __attribute__((ext_vector_type(2))) unsigned int u32x2;

__device__ __forceinline__ unsigned short f2bf(float f) {
  unsigned int u = __float_as_uint(f);
  u += 0x7FFFu + ((u >> 16) & 1u);          // RNE
  return (unsigned short)(u >> 16);
}
__device__ __forceinline__ float bf2f(unsigned short h) {
  return __uint_as_float(((unsigned int)h) << 16);
}
__device__ __forceinline__ float fexp(float x) {   // e^x via v_exp_f32
  return __builtin_amdgcn_exp2f(x * 1.44269504088896340736f);
}
__device__ __forceinline__ float sigm(float x) {
  return 1.0f / (1.0f + fexp(-x));
}

template <int CTRL>
__device__ __forceinline__ float dpp_add(float v) {
  int x = __builtin_amdgcn_update_dpp(0, __float_as_int(v), CTRL, 0xF, 0xF, true);
  return v + __int_as_float(x);
}
// sum within aligned quads of lanes; all 4 lanes hold the quad sum
__device__ __forceinline__ float quad_sum(float v) {
  v = dpp_add<0xB1>(v);   // quad_perm [1,0,3,2]
  v = dpp_add<0x4E>(v);   // quad_perm [2,3,0,1]
  return v;
}

// ---------------------------------------------------------------- casts ----
__global__ void cast_all_kernel(const float* __restrict__ x, const float* __restrict__ w1,
                                const float* __restrict__ w2, const float* __restrict__ w3,
                                const float* __restrict__ dtw,
                                unsigned short* __restrict__ xbf, unsigned short* __restrict__ w1bf,
                                unsigned short* __restrict__ w2bf, unsigned short* __restrict__ w3bf,
                                unsigned short* __restrict__ dtwbf) {
  int i = blockIdx.x * 256 + threadIdx.x;
  const int n_x = M_ROWS * DMODEL;
  const int n_w1 = 2 * DINNER * DMODEL;
  const int n_w3 = DMODEL * DINNER;
  const int n_w2 = 128 * DINNER;
  const int n_dtw = DINNER * 64;
  if (i < n_x)  { xbf[i] = f2bf(x[i]); return; }  i -= n_x;
  if (i < n_w1) { w1bf[i] = f2bf(w1[i]); return; } i -= n_w1;
  if (i < n_w3) { w3bf[i] = f2bf(w3[i]); return; } i -= n_w3;
  if (i < n_w2) {
    int row = i / DINNER, col = i - row * DINNER;
    w2bf[i] = (row < (DTRANK + 2 * DSTATE)) ? f2bf(w2[row * DINNER + col]) : (unsigned short)0;
    return;
  }
  i -= n_w2;
  if (i < n_dtw) {
    int row = i >> 6, col = i & 63;
    dtwbf[i] = (col < DTRANK) ? f2bf(dtw[row * DTRANK + col]) : (unsigned short)0;
  }
}

__global__ void cast_dtlow_kernel(const float* __restrict__ xdbl, unsigned short* __restrict__ out) {
  int i = blockIdx.x * 256 + threadIdx.x;   // 4096*64
  int row = i >> 6, col = i & 63;
  out[i] = (col < DTRANK) ? f2bf(xdbl[row * 128 + col]) : (unsigned short)0;
}

// --------------------------------------------------- bf16 MFMA GEMM (B^T) ----
// C[m][n] = sum_k A[m][k]*Bt[n][k]. EPI: 0 plain; 2 softplus(acc + bias[row]).
template <int EPI>
__global__ __launch_bounds__(256, 2) void gemm_bt(
    const unsigned short* __restrict__ A, const unsigned short* __restrict__ Bt,
    float* __restrict__ C, int K, int ldc, const float* __restrict__ bias) {
  __shared__ unsigned short As[128 * 40];
  __shared__ unsigned short Bs[128 * 40];
  const int tid = threadIdx.x;
  const int m0 = blockIdx.x * 128;
  const int n0 = blockIdx.y * 128;
  const int lane = tid & 63;
  const int wave = tid >> 6;
  const int wr = (wave >> 1) * 64, wc = (wave & 1) * 64;
  const int lm = lane & 15, q = lane >> 4;
  const int r = tid >> 2, sg = (tid & 3) * 8;

  f32x4 acc[4][4] = {};

  for (int k0 = 0; k0 < K; k0 += 32) {
    u32x4 a0 = *(const u32x4*)(A + (size_t)(m0 + r) * K + k0 + sg);
    u32x4 a1 = *(const u32x4*)(A + (size_t)(m0 + r + 64) * K + k0 + sg);
    u32x4 b0 = *(const u32x4*)(Bt + (size_t)(n0 + r) * K + k0 + sg);
    u32x4 b1 = *(const u32x4*)(Bt + (size_t)(n0 + r + 64) * K + k0 + sg);
    __syncthreads();
    *(u32x4*)&As[r * 40 + sg] = a0;
    *(u32x4*)&As[(r + 64) * 40 + sg] = a1;
    *(u32x4*)&Bs[r * 40 + sg] = b0;
    *(u32x4*)&Bs[(r + 64) * 40 + sg] = b1;
    __syncthreads();
    bf16x8 af[4], bq[4];
#pragma unroll
    for (int mt = 0; mt < 4; mt++)
      af[mt] = *(const bf16x8*)&As[(wr + mt * 16 + lm) * 40 + q * 8];
#pragma unroll
    for (int nt = 0; nt < 4; nt++)
      bq[nt] = *(const bf16x8*)&Bs[(wc + nt * 16 + lm) * 40 + q * 8];
#pragma unroll
    for (int mt = 0; mt < 4; mt++)
#pragma unroll
      for (int nt = 0; nt < 4; nt++)
        acc[mt][nt] = __builtin_amdgcn_mfma_f32_16x16x32_bf16(af[mt], bq[nt], acc[mt][nt], 0, 0, 0);
  }

#pragma unroll
  for (int mt = 0; mt < 4; mt++) {
    int row0 = m0 + wr + mt * 16 + q * 4;
    float bs4[4];
    if (EPI == 2) {
#pragma unroll
      for (int i = 0; i < 4; i++) bs4[i] = bias[row0 + i];
    }
#pragma unroll
    for (int nt = 0; nt < 4; nt++) {
      int col = n0 + wc + nt * 16 + lm;
#pragma unroll
      for (int i = 0; i < 4; i++) {
        float v = acc[mt][nt][i];
        if (EPI == 2) {                      // softplus(v + bias[row]), stable
          v += bs4[i];
          v = (v > 15.f) ? v : log1pf(fexp(v));
        }
        C[(size_t)(row0 + i) * ldc + col] = v;
      }
    }
  }
}

// ------------------------------------------------- depthwise conv + SiLU ----
__global__ void conv_silu_kernel(const float* __restrict__ xz, const float* __restrict__ cw,
                                 const float* __restrict__ cb, unsigned short* __restrict__ xcbf) {
  int idx = blockIdx.x * 256 + threadIdx.x;
  if (idx >= B_SZ * L_SEQ * DINNER) return;
  int d = idx % DINNER;
  int bl = idx / DINNER;
  int l = bl & (L_SEQ - 1);
  float acc = cb[d];
#pragma unroll
  for (int k = 0; k < 4; k++) {
    int ll = l - 3 + k;
    if (ll >= 0) acc += cw[d * 4 + k] * xz[(size_t)(bl - 3 + k) * 3072 + d];
  }
  xcbf[idx] = f2bf(acc * sigm(acc));
}

// ----------------------------------------------------- transpose kernels ----
// xc [4096][1536] bf16 -> xcT [1536][4096] bf16. 64x64 tiles.
__global__ __launch_bounds__(256) void transpose_bf16(const unsigned short* __restrict__ in,
                                                      unsigned short* __restrict__ out) {
  __shared__ unsigned short tl[64 * 80];
  const int r0 = blockIdx.x * 64;   // row tile in input (4096 dim)
  const int c0 = blockIdx.y * 64;   // col tile (1536 dim)
  const int tid = threadIdx.x;
#pragma unroll
  for (int it = 0; it < 2; it++) {
    int idx = tid + it * 256;
    int rr = idx >> 3, cs = idx & 7;
    u32x4 v = *(const u32x4*)(in + (size_t)(r0 + rr) * DINNER + c0 + cs * 8);
    *(u32x4*)&tl[rr * 80 + cs * 8] = v;
  }
  __syncthreads();
#pragma unroll
  for (int it = 0; it < 2; it++) {
    int idx = tid + it * 256;
    int cc = idx & 63, rs = idx >> 6;   // rs in 0..3 (+4*it handled below)
    rs += it * 0;                        // idx>>6 spans 0..3 for it=0, 4..7 for it=1 via idx
    rs = (tid + it * 256) >> 6;
    unsigned int w[4];
#pragma unroll
    for (int p = 0; p < 4; p++) {
      unsigned int lo = tl[(rs * 8 + 2 * p) * 80 + cc];
      unsigned int hi = tl[(rs * 8 + 2 * p + 1) * 80 + cc];
      w[p] = lo | (hi << 16);
    }
    *(u32x4*)(out + (size_t)(c0 + cc) * M_ROWS + r0 + rs * 8) = *(u32x4*)w;
  }
}

// z-half of xz [4096][3072] f32 -> silu -> szT [1536][4096] bf16. 64x64 tiles.
__global__ __launch_bounds__(256) void transpose_silu(const float* __restrict__ xz,
                                                      unsigned short* __restrict__ out) {
  __shared__ float tl[64 * 68];
  const int r0 = blockIdx.x * 64;
  const int c0 = blockIdx.y * 64;
  const int tid = threadIdx.x;
#pragma unroll
  for (int it = 0; it < 4; it++) {
    int idx = tid + it * 256;
    int rr = idx >> 4, cs = idx & 15;
    f32x4 v = *(const f32x4*)(xz + (size_t)(r0 + rr) * 3072 + DINNER + c0 + cs * 4);
#pragma unroll
    for (int p = 0; p < 4; p++) v[p] = v[p] * sigm(v[p]);
    *(f32x4*)&tl[rr * 68 + cs * 4] = v;
  }
  __syncthreads();
#pragma unroll
  for (int it = 0; it < 2; it++) {
    int idx = tid + it * 256;
    int cc = idx & 63, rs = idx >> 6;
    unsigned int w[4];
#pragma unroll
    for (int p = 0; p < 4; p++) {
      unsigned int lo = f2bf(tl[(rs * 8 + 2 * p) * 68 + cc]);
      unsigned int hi = f2bf(tl[(rs * 8 + 2 * p + 1) * 68 + cc]);
      w[p] = lo | (hi << 16);
    }
    *(u32x4*)(out + (size_t)(c0 + cc) * M_ROWS + r0 + rs * 8) = *(u32x4*)w;
  }
}

// x_dbl cols 48..79 -> BCt[b][j][l]  (j<16: B_s, j>=16: C_s)
__global__ void bct_kernel(const float* __restrict__ xdbl, float* __restrict__ BCt) {
  int t = blockIdx.x * 256 + threadIdx.x;   // 32768 total
  int l4 = t & 511;
  int j  = (t >> 9) & 31;
  int b  = (t >> 14) & 1;
  f32x4 o;
#pragma unroll
  for (int i = 0; i < 4; i++)
    o[i] = xdbl[((size_t)b * L_SEQ + l4 * 4 + i) * 128 + DTRANK + j];
  *(f32x4*)(BCt + ((size_t)b * 32 + j) * L_SEQ + l4 * 4) = o;
}

// -------------------------------------------- single-pass selective scan ----
// 64-thr block = one wave = 4 channels x 16 states; walks all L=2048 steps.
// Operands pre-transposed: contiguous along l. Quad-DPP reduce + packed LDS
// partials; chunk epilogue fuses +xc*D, *silu(z), bf16 store.
__global__ __launch_bounds__(64) void scan_single(
    const float* __restrict__ dtT, const unsigned short* __restrict__ xcT,
    const float* __restrict__ BCt, const unsigned short* __restrict__ szT,
    const float* __restrict__ A_log, const float* __restrict__ Dp,
    unsigned short* __restrict__ ybf) {
  __shared__ float ysh[16 * 68];
  const int lane = threadIdx.x;
  const int s = lane & 15, dl = lane >> 4;
  const int d = blockIdx.x * 4 + dl;
  const int b = blockIdx.y;
  const size_t rbase = (size_t)b * L_SEQ;
  const float a2 = -fexp(A_log[d * 16 + s]) * 1.44269504f;
  const float dpv = Dp[d];
  const float* dtrow = dtT + (size_t)d * M_ROWS + rbase;
  const unsigned short* xcrow = xcT + (size_t)d * M_ROWS + rbase;
  const unsigned short* szrow = szT + (size_t)d * M_ROWS + rbase;
  const float* Brow = BCt + ((size_t)b * 32 + s) * L_SEQ;
  const float* Crow = BCt + ((size_t)b * 32 + 16 + s) * L_SEQ;
  float* ywp = &ysh[(dl * 4 + (s >> 2)) * 68 + (s & 3)];   // packed-store base
  const bool sb0 = (s & 1) != 0, sb1 = (s & 2) != 0;
  float h = 0.f;

  // prefetch group 0
  f32x4 ndt0 = *(const f32x4*)(dtrow);
  f32x4 ndt1 = *(const f32x4*)(dtrow + 4);
  u32x4 nxc  = *(const u32x4*)(xcrow);
  f32x4 nB0  = *(const f32x4*)(Brow);
  f32x4 nB1  = *(const f32x4*)(Brow + 4);
  f32x4 nC0  = *(const f32x4*)(Crow);
  f32x4 nC1  = *(const f32x4*)(Crow + 4);

  for (int c = 0; c < NCHUNK; c++) {
#pragma unroll 1
    for (int g = 0; g < 8; g++) {
      f32x4 dt0 = ndt0, dt1 = ndt1, B0 = nB0, B1 = nB1, C0 = nC0, C1 = nC1;
      u32x4 xcv = nxc;
      int ln = c * 64 + g * 8 + 8;
      if (ln == L_SEQ) ln = 0;            // uniform wrap, avoids OOB
      ndt0 = *(const f32x4*)(dtrow + ln);
      ndt1 = *(const f32x4*)(dtrow + ln + 4);
      nxc  = *(const u32x4*)(xcrow + ln);
      nB0  = *(const f32x4*)(Brow + ln);
      nB1  = *(const f32x4*)(Brow + ln + 4);
      nC0  = *(const f32x4*)(Crow + ln);
      nC1  = *(const f32x4*)(Crow + ln + 4);

      float xf[8];
#pragma unroll
      for (int jp = 0; jp < 4; jp++) {
        unsigned int w = xcv[jp];
        xf[2 * jp]     = __uint_as_float(w << 16);
        xf[2 * jp + 1] = __uint_as_float(w & 0xFFFF0000u);
      }
      float p[8];
#pragma unroll
      for (int j = 0; j < 8; j++) {
        float dtj = (j < 4) ? dt0[j] : dt1[j - 4];
        float Bj  = (j < 4) ? B0[j]  : B1[j - 4];
        float Cj  = (j < 4) ? C0[j]  : C1[j - 4];
        float a = __builtin_amdgcn_exp2f(dtj * a2);
        h = a * h + dtj * xf[j] * Bj;
        p[j] = h * Cj;
      }
#pragma unroll
      for (int half = 0; half < 2; half++) {
        float q0 = quad_sum(p[half * 4 + 0]);
        float q1 = quad_sum(p[half * 4 + 1]);
        float q2 = quad_sum(p[half * 4 + 2]);
        float q3 = quad_sum(p[half * 4 + 3]);
        float v01 = sb0 ? q1 : q0;
        float v23 = sb0 ? q3 : q2;
        ywp[g * 8 + half * 4] = sb1 ? v23 : v01;   // 1 ds_write_b32, 2-way banks
      }
    }
    // ---- chunk epilogue: lane covers (ch=dl, l = s*4 .. s*4+3) ----
    {
      f32x4 y0 = *(const f32x4*)&ysh[(dl * 4 + 0) * 68 + s * 4];
      f32x4 y1 = *(const f32x4*)&ysh[(dl * 4 + 1) * 68 + s * 4];
      f32x4 y2 = *(const f32x4*)&ysh[(dl * 4 + 2) * 68 + s * 4];
      f32x4 y3 = *(const f32x4*)&ysh[(dl * 4 + 3) * 68 + s * 4];
      f32x4 ys = y0 + y1 + y2 + y3;
      const int le = c * 64 + s * 4;
      u32x2 xcu = *(const u32x2*)(xcrow + le);
      u32x2 szu = *(const u32x2*)(szrow + le);
      float xcf[4] = {__uint_as_float(xcu[0] << 16), __uint_as_float(xcu[0] & 0xFFFF0000u),
                      __uint_as_float(xcu[1] << 16), __uint_as_float(xcu[1] & 0xFFFF0000u)};
      float szf[4] = {__uint_as_float(szu[0] << 16), __uint_as_float(szu[0] & 0xFFFF0000u),
                      __uint_as_float(szu[1] << 16), __uint_as_float(szu[1] & 0xFFFF0000u)};
      size_t rr0 = rbase + le;
#pragma unroll
      for (int i = 0; i < 4; i++) {
        float yv = ys[i] + xcf[i] * dpv;
        ybf[(rr0 + i) * DINNER + d] = f2bf(yv * szf[i]);
      }
    }
  }
}

// -------------------------------------------------------------- launcher ----
extern "C" void kernel_launch(void* const* d_in, const int* in_sizes, int n_in,
                              void* d_out, int out_size, void* d_ws, size_t ws_size,
                              hipStream_t stream) {
  const float* x    = (const float*)d_in[0];
  const float* w1   = (const float*)d_in[1];
  const float* cw   = (const float*)d_in[2];
  const float* cb   = (const float*)d_in[3];
  const float* alog = (const float*)d_in[4];
  const float* Dp   = (const float*)d_in[5];
  const float* w2   = (const float*)d_in[6];
  const float* dtw  = (const float*)d_in[7];
  const float* dtb  = (const float*)d_in[8];
  const float* w3   = (const float*)d_in[9];
  float* out = (float*)d_out;
  char* ws = (char*)d_ws;

  size_t off = 0;
  auto alloc = [&](size_t bytes) { size_t o = off; off += (bytes + 255) & ~(size_t)255; return o; };
  // xz region is reused: after conv+szT consume it, dtT and ybf overlay it.
  char*           xzr   = ws + alloc((size_t)M_ROWS * 3072 * 4);            // 50.3 MB
  float*          xz    = (float*)xzr;
  float*          dtT   = (float*)xzr;                                      // overlay [1536][4096] f32
  unsigned short* ybf   = (unsigned short*)(xzr + (size_t)DINNER * M_ROWS * 4); // overlay
  float*          xdbl  = (float*)(ws + alloc((size_t)M_ROWS * 128 * 4));
  unsigned short* xbf   = (unsigned short*)(ws + alloc((size_t)M_ROWS * DMODEL * 2));
  unsigned short* w1bf  = (unsigned short*)(ws + alloc((size_t)2 * DINNER * DMODEL * 2));
  unsigned short* w2bf  = (unsigned short*)(ws + alloc((size_t)128 * DINNER * 2));
  unsigned short* w3bf  = (unsigned short*)(ws + alloc((size_t)DMODEL * DINNER * 2));
  unsigned short* dtlbf = (unsigned short*)(ws + alloc((size_t)M_ROWS * 64 * 2));
  unsigned short* dtwbf = (unsigned short*)(ws + alloc((size_t)DINNER * 64 * 2));
  unsigned short* xcbf  = (unsigned short*)(ws + alloc((size_t)M_ROWS * DINNER * 2));
  unsigned short* xcT   = (unsigned short*)(ws + alloc((size_t)DINNER * M_ROWS * 2));
  unsigned short* szbf  = (unsigned short*)(ws + alloc((size_t)DINNER * M_ROWS * 2));
  float*          BCt   = (float*)(ws + alloc((size_t)B_SZ * 32 * L_SEQ * 4));

  // 1. cast inputs/weights to bf16
  cast_all_kernel<<<27264, 256, 0, stream>>>(x, w1, w2, w3, dtw, xbf, w1bf, w2bf, w3bf, dtwbf);
  // 2. xz = x @ W_in^T  [4096 x 3072]
  gemm_bt<0><<<dim3(32, 24), 256, 0, stream>>>(xbf, w1bf, xz, DMODEL, 3072, nullptr);
  // 3. depthwise conv + SiLU -> xc (bf16, row-major)
  conv_silu_kernel<<<24576, 256, 0, stream>>>(xz, cw, cb, xcbf);
  // 4. szT = silu(z)^T (bf16)  [consumes xz z-half; xz dead after this]
  transpose_silu<<<dim3(64, 24), 256, 0, stream>>>(xz, szbf);
  // 5. xcT = xc^T (bf16)
  transpose_bf16<<<dim3(64, 24), 256, 0, stream>>>(xcbf, xcT);
  // 6. x_dbl = xc @ W_x^T  [4096 x 128]
  gemm_bt<0><<<dim3(32, 1), 256, 0, stream>>>(xcbf, w2bf, xdbl, DINNER, 128, nullptr);
  // 7. B/C rows transposed
  bct_kernel<<<128, 256, 0, stream>>>(xdbl, BCt);
  // 8. dt_low -> bf16 padded K=64
  cast_dtlow_kernel<<<1024, 256, 0, stream>>>(xdbl, dtlbf);
  // 9. dtT = softplus(W_dt @ dt_low^T + b)  -> [1536][4096] (transposed GEMM, overlays xz)
  gemm_bt<2><<<dim3(12, 32), 256, 0, stream>>>(dtwbf, dtlbf, dtT, 64, M_ROWS, dtb);
  // 10. single-pass selective scan + fused epilogue -> ybf
  scan_single<<<dim3(384, 2), 64, 0, stream>>>(dtT, xcT, BCt, szbf, alog, Dp, ybf);
  // 11. out = y @ W_out^T  [4096 x 768]
  gemm_bt<0><<<dim3(32, 6), 256, 0, stream>>>(ybf, w3bf, out, DINNER, 768, nullptr);
}

// Round 4
// 390.559 us; speedup vs baseline: 1.0419x; 1.0419x over previous
//
#include <hip/hip_runtime.h>
#include <stdint.h>

#define B_SZ    2
#define L_SEQ   2048
#define DMODEL  768
#define DSTATE  16
#define DINNER  1536
#define DTRANK  48
#define M_ROWS  4096      // B*L
#define NCHUNK  32

typedef __attribute__((ext_vector_type(8))) short bf16x8;
typedef __attribute__((ext_vector_type(4))) float f32x4;
typedef __attribute__((ext_vector_type(4))) unsigned int u32x4;
typedef __attribute__((ext_vector_type(2))) unsigned int u32x2;

__device__ __forceinline__ unsigned short f2bf(float f) {
  unsigned int u = __float_as_uint(f);
  u += 0x7FFFu + ((u >> 16) & 1u);          // RNE
  return (unsigned short)(u >> 16);
}
__device__ __forceinline__ float bf2f(unsigned short h) {
  return __uint_as_float(((unsigned int)h) << 16);
}
__device__ __forceinline__ float fexp(float x) {   // e^x via v_exp_f32
  return __builtin_amdgcn_exp2f(x * 1.44269504088896340736f);
}
__device__ __forceinline__ float sigm(float x) {
  return 1.0f / (1.0f + fexp(-x));
}

template <int CTRL>
__device__ __forceinline__ float dpp_add(float v) {
  int x = __builtin_amdgcn_update_dpp(0, __float_as_int(v), CTRL, 0xF, 0xF, true);
  return v + __int_as_float(x);
}
// sum within aligned quads of lanes; all 4 lanes hold the quad sum
__device__ __forceinline__ float quad_sum(float v) {
  v = dpp_add<0xB1>(v);   // quad_perm [1,0,3,2]
  v = dpp_add<0x4E>(v);   // quad_perm [2,3,0,1]
  return v;
}

// ---------------------------------------------------------------- casts ----
__global__ void cast_all_kernel(const float* __restrict__ x, const float* __restrict__ w1,
                                const float* __restrict__ w2, const float* __restrict__ w3,
                                const float* __restrict__ dtw,
                                unsigned short* __restrict__ xbf, unsigned short* __restrict__ w1bf,
                                unsigned short* __restrict__ w2bf, unsigned short* __restrict__ w3bf,
                                unsigned short* __restrict__ dtwbf) {
  int i = blockIdx.x * 256 + threadIdx.x;
  const int n_x = M_ROWS * DMODEL;
  const int n_w1 = 2 * DINNER * DMODEL;
  const int n_w3 = DMODEL * DINNER;
  const int n_w2 = 128 * DINNER;
  const int n_dtw = DINNER * 64;
  if (i < n_x)  { xbf[i] = f2bf(x[i]); return; }  i -= n_x;
  if (i < n_w1) { w1bf[i] = f2bf(w1[i]); return; } i -= n_w1;
  if (i < n_w3) { w3bf[i] = f2bf(w3[i]); return; } i -= n_w3;
  if (i < n_w2) {
    int row = i / DINNER, col = i - row * DINNER;
    w2bf[i] = (row < (DTRANK + 2 * DSTATE)) ? f2bf(w2[row * DINNER + col]) : (unsigned short)0;
    return;
  }
  i -= n_w2;
  if (i < n_dtw) {
    int row = i >> 6, col = i & 63;
    dtwbf[i] = (col < DTRANK) ? f2bf(dtw[row * DTRANK + col]) : (unsigned short)0;
  }
}

__global__ void cast_dtlow_kernel(const float* __restrict__ xdbl, unsigned short* __restrict__ out) {
  int i = blockIdx.x * 256 + threadIdx.x;   // 4096*64
  int row = i >> 6, col = i & 63;
  out[i] = (col < DTRANK) ? f2bf(xdbl[row * 128 + col]) : (unsigned short)0;
}

// --------------------------------------------------- bf16 MFMA GEMM (B^T) ----
// C[m][n] = sum_k A[m][k]*Bt[n][k]. EPI: 0 plain; 2 softplus(acc + bias[row]).
template <int EPI>
__global__ __launch_bounds__(256, 2) void gemm_bt(
    const unsigned short* __restrict__ A, const unsigned short* __restrict__ Bt,
    float* __restrict__ C, int K, int ldc, const float* __restrict__ bias) {
  __shared__ unsigned short As[128 * 40];
  __shared__ unsigned short Bs[128 * 40];
  const int tid = threadIdx.x;
  const int m0 = blockIdx.x * 128;
  const int n0 = blockIdx.y * 128;
  const int lane = tid & 63;
  const int wave = tid >> 6;
  const int wr = (wave >> 1) * 64, wc = (wave & 1) * 64;
  const int lm = lane & 15, q = lane >> 4;
  const int r = tid >> 2, sg = (tid & 3) * 8;

  f32x4 acc[4][4] = {};

  for (int k0 = 0; k0 < K; k0 += 32) {
    u32x4 a0 = *(const u32x4*)(A + (size_t)(m0 + r) * K + k0 + sg);
    u32x4 a1 = *(const u32x4*)(A + (size_t)(m0 + r + 64) * K + k0 + sg);
    u32x4 b0 = *(const u32x4*)(Bt + (size_t)(n0 + r) * K + k0 + sg);
    u32x4 b1 = *(const u32x4*)(Bt + (size_t)(n0 + r + 64) * K + k0 + sg);
    __syncthreads();
    *(u32x4*)&As[r * 40 + sg] = a0;
    *(u32x4*)&As[(r + 64) * 40 + sg] = a1;
    *(u32x4*)&Bs[r * 40 + sg] = b0;
    *(u32x4*)&Bs[(r + 64) * 40 + sg] = b1;
    __syncthreads();
    bf16x8 af[4], bq[4];
#pragma unroll
    for (int mt = 0; mt < 4; mt++)
      af[mt] = *(const bf16x8*)&As[(wr + mt * 16 + lm) * 40 + q * 8];
#pragma unroll
    for (int nt = 0; nt < 4; nt++)
      bq[nt] = *(const bf16x8*)&Bs[(wc + nt * 16 + lm) * 40 + q * 8];
#pragma unroll
    for (int mt = 0; mt < 4; mt++)
#pragma unroll
      for (int nt = 0; nt < 4; nt++)
        acc[mt][nt] = __builtin_amdgcn_mfma_f32_16x16x32_bf16(af[mt], bq[nt], acc[mt][nt], 0, 0, 0);
  }

#pragma unroll
  for (int mt = 0; mt < 4; mt++) {
    int row0 = m0 + wr + mt * 16 + q * 4;
    float bs4[4];
    if (EPI == 2) {
#pragma unroll
      for (int i = 0; i < 4; i++) bs4[i] = bias[row0 + i];
    }
#pragma unroll
    for (int nt = 0; nt < 4; nt++) {
      int col = n0 + wc + nt * 16 + lm;
#pragma unroll
      for (int i = 0; i < 4; i++) {
        float v = acc[mt][nt][i];
        if (EPI == 2) {                      // softplus(v + bias[row]), stable
          v += bs4[i];
          v = (v > 15.f) ? v : log1pf(fexp(v));
        }
        C[(size_t)(row0 + i) * ldc + col] = v;
      }
    }
  }
}

// ------------------------------------------------- depthwise conv + SiLU ----
__global__ void conv_silu_kernel(const float* __restrict__ xz, const float* __restrict__ cw,
                                 const float* __restrict__ cb, unsigned short* __restrict__ xcbf) {
  int idx = blockIdx.x * 256 + threadIdx.x;
  if (idx >= B_SZ * L_SEQ * DINNER) return;
  int d = idx % DINNER;
  int bl = idx / DINNER;
  int l = bl & (L_SEQ - 1);
  float acc = cb[d];
#pragma unroll
  for (int k = 0; k < 4; k++) {
    int ll = l - 3 + k;
    if (ll >= 0) acc += cw[d * 4 + k] * xz[(size_t)(bl - 3 + k) * 3072 + d];
  }
  xcbf[idx] = f2bf(acc * sigm(acc));
}

// ----------------------------------------------------- transpose kernels ----
__global__ __launch_bounds__(256) void transpose_bf16(const unsigned short* __restrict__ in,
                                                      unsigned short* __restrict__ out) {
  __shared__ unsigned short tl[64 * 80];
  const int r0 = blockIdx.x * 64;
  const int c0 = blockIdx.y * 64;
  const int tid = threadIdx.x;
#pragma unroll
  for (int it = 0; it < 2; it++) {
    int idx = tid + it * 256;
    int rr = idx >> 3, cs = idx & 7;
    u32x4 v = *(const u32x4*)(in + (size_t)(r0 + rr) * DINNER + c0 + cs * 8);
    *(u32x4*)&tl[rr * 80 + cs * 8] = v;
  }
  __syncthreads();
#pragma unroll
  for (int it = 0; it < 2; it++) {
    int idx = tid + it * 256;
    int cc = idx & 63, rs = idx >> 6;
    unsigned int w[4];
#pragma unroll
    for (int p = 0; p < 4; p++) {
      unsigned int lo = tl[(rs * 8 + 2 * p) * 80 + cc];
      unsigned int hi = tl[(rs * 8 + 2 * p + 1) * 80 + cc];
      w[p] = lo | (hi << 16);
    }
    *(u32x4*)(out + (size_t)(c0 + cc) * M_ROWS + r0 + rs * 8) = *(u32x4*)w;
  }
}

__global__ __launch_bounds__(256) void transpose_silu(const float* __restrict__ xz,
                                                      unsigned short* __restrict__ out) {
  __shared__ float tl[64 * 68];
  const int r0 = blockIdx.x * 64;
  const int c0 = blockIdx.y * 64;
  const int tid = threadIdx.x;
#pragma unroll
  for (int it = 0; it < 4; it++) {
    int idx = tid + it * 256;
    int rr = idx >> 4, cs = idx & 15;
    f32x4 v = *(const f32x4*)(xz + (size_t)(r0 + rr) * 3072 + DINNER + c0 + cs * 4);
#pragma unroll
    for (int p = 0; p < 4; p++) v[p] = v[p] * sigm(v[p]);
    *(f32x4*)&tl[rr * 68 + cs * 4] = v;
  }
  __syncthreads();
#pragma unroll
  for (int it = 0; it < 2; it++) {
    int idx = tid + it * 256;
    int cc = idx & 63, rs = idx >> 6;
    unsigned int w[4];
#pragma unroll
    for (int p = 0; p < 4; p++) {
      unsigned int lo = f2bf(tl[(rs * 8 + 2 * p) * 68 + cc]);
      unsigned int hi = f2bf(tl[(rs * 8 + 2 * p + 1) * 68 + cc]);
      w[p] = lo | (hi << 16);
    }
    *(u32x4*)(out + (size_t)(c0 + cc) * M_ROWS + r0 + rs * 8) = *(u32x4*)w;
  }
}

// x_dbl cols 48..79 -> BCt[b][j][l]  (j<16: B_s, j>=16: C_s)
__global__ void bct_kernel(const float* __restrict__ xdbl, float* __restrict__ BCt) {
  int t = blockIdx.x * 256 + threadIdx.x;   // 32768 total
  int l4 = t & 511;
  int j  = (t >> 9) & 31;
  int b  = (t >> 14) & 1;
  f32x4 o;
#pragma unroll
  for (int i = 0; i < 4; i++)
    o[i] = xdbl[((size_t)b * L_SEQ + l4 * 4 + i) * 128 + DTRANK + j];
  *(f32x4*)(BCt + ((size_t)b * 32 + j) * L_SEQ + l4 * 4) = o;
}

// -------------------------------------------- single-pass selective scan ----
// 64-thr block = one wave = 4 channels x 16 states; walks all L=2048 steps.
// 4-group-deep software pipeline: circular register buffer, each 8-step group
// consumes loads issued 4 groups (32 steps) earlier -> ~28 KB in flight/wave.
struct Grp { f32x4 dt0, dt1, B0, B1, C0, C1; u32x4 xc; };

__device__ __forceinline__ void load_grp(Grp& gb, const float* dtrow,
                                         const unsigned short* xcrow,
                                         const float* Brow, const float* Crow, int ln) {
  gb.dt0 = *(const f32x4*)(dtrow + ln);
  gb.dt1 = *(const f32x4*)(dtrow + ln + 4);
  gb.xc  = *(const u32x4*)(xcrow + ln);
  gb.B0  = *(const f32x4*)(Brow + ln);
  gb.B1  = *(const f32x4*)(Brow + ln + 4);
  gb.C0  = *(const f32x4*)(Crow + ln);
  gb.C1  = *(const f32x4*)(Crow + ln + 4);
}

__global__ __launch_bounds__(64) void scan_single(
    const float* __restrict__ dtT, const unsigned short* __restrict__ xcT,
    const float* __restrict__ BCt, const unsigned short* __restrict__ szT,
    const float* __restrict__ A_log, const float* __restrict__ Dp,
    unsigned short* __restrict__ ybf) {
  __shared__ float ysh[16 * 68];
  const int lane = threadIdx.x;
  const int s = lane & 15, dl = lane >> 4;
  const int d = blockIdx.x * 4 + dl;
  const int b = blockIdx.y;
  const size_t rbase = (size_t)b * L_SEQ;
  const float a2 = -fexp(A_log[d * 16 + s]) * 1.44269504f;
  const float dpv = Dp[d];
  const float* dtrow = dtT + (size_t)d * M_ROWS + rbase;
  const unsigned short* xcrow = xcT + (size_t)d * M_ROWS + rbase;
  const unsigned short* szrow = szT + (size_t)d * M_ROWS + rbase;
  const float* Brow = BCt + ((size_t)b * 32 + s) * L_SEQ;
  const float* Crow = BCt + ((size_t)b * 32 + 16 + s) * L_SEQ;
  float* ywp = &ysh[(dl * 4 + (s >> 2)) * 68 + (s & 3)];   // packed-store base
  const bool sb0 = (s & 1) != 0, sb1 = (s & 2) != 0;
  float h = 0.f;

  Grp buf[4];
#pragma unroll
  for (int p = 0; p < 4; p++) load_grp(buf[p], dtrow, xcrow, Brow, Crow, p * 8);

#pragma unroll 1
  for (int c = 0; c < NCHUNK; c++) {
#pragma unroll
    for (int g = 0; g < 8; g++) {
      Grp& gb = buf[g & 3];
      f32x4 dt0 = gb.dt0, dt1 = gb.dt1, B0 = gb.B0, B1 = gb.B1, C0 = gb.C0, C1 = gb.C1;
      u32x4 xcv = gb.xc;
      // immediately re-issue this slot's loads 4 groups ahead (wrap at 256)
      int ln = ((c * 8 + g + 4) & 255) * 8;
      load_grp(gb, dtrow, xcrow, Brow, Crow, ln);

      float xf[8];
#pragma unroll
      for (int jp = 0; jp < 4; jp++) {
        unsigned int w = xcv[jp];
        xf[2 * jp]     = __uint_as_float(w << 16);
        xf[2 * jp + 1] = __uint_as_float(w & 0xFFFF0000u);
      }
      float p8[8];
#pragma unroll
      for (int j = 0; j < 8; j++) {
        float dtj = (j < 4) ? dt0[j] : dt1[j - 4];
        float Bj  = (j < 4) ? B0[j]  : B1[j - 4];
        float Cj  = (j < 4) ? C0[j]  : C1[j - 4];
        float a = __builtin_amdgcn_exp2f(dtj * a2);
        h = a * h + dtj * xf[j] * Bj;
        p8[j] = h * Cj;
      }
#pragma unroll
      for (int half = 0; half < 2; half++) {
        float q0 = quad_sum(p8[half * 4 + 0]);
        float q1 = quad_sum(p8[half * 4 + 1]);
        float q2 = quad_sum(p8[half * 4 + 2]);
        float q3 = quad_sum(p8[half * 4 + 3]);
        float v01 = sb0 ? q1 : q0;
        float v23 = sb0 ? q3 : q2;
        ywp[g * 8 + half * 4] = sb1 ? v23 : v01;   // 1 ds_write_b32, 2-way banks
      }
    }
    // ---- chunk epilogue: lane covers (ch=dl, l = s*4 .. s*4+3) ----
    {
      f32x4 y0 = *(const f32x4*)&ysh[(dl * 4 + 0) * 68 + s * 4];
      f32x4 y1 = *(const f32x4*)&ysh[(dl * 4 + 1) * 68 + s * 4];
      f32x4 y2 = *(const f32x4*)&ysh[(dl * 4 + 2) * 68 + s * 4];
      f32x4 y3 = *(const f32x4*)&ysh[(dl * 4 + 3) * 68 + s * 4];
      f32x4 ys = y0 + y1 + y2 + y3;
      const int le = c * 64 + s * 4;
      u32x2 xcu = *(const u32x2*)(xcrow + le);
      u32x2 szu = *(const u32x2*)(szrow + le);
      float xcf[4] = {__uint_as_float(xcu[0] << 16), __uint_as_float(xcu[0] & 0xFFFF0000u),
                      __uint_as_float(xcu[1] << 16), __uint_as_float(xcu[1] & 0xFFFF0000u)};
      float szf[4] = {__uint_as_float(szu[0] << 16), __uint_as_float(szu[0] & 0xFFFF0000u),
                      __uint_as_float(szu[1] << 16), __uint_as_float(szu[1] & 0xFFFF0000u)};
      size_t rr0 = rbase + le;
#pragma unroll
      for (int i = 0; i < 4; i++) {
        float yv = ys[i] + xcf[i] * dpv;
        ybf[(rr0 + i) * DINNER + d] = f2bf(yv * szf[i]);
      }
    }
  }
}

// -------------------------------------------------------------- launcher ----
extern "C" void kernel_launch(void* const* d_in, const int* in_sizes, int n_in,
                              void* d_out, int out_size, void* d_ws, size_t ws_size,
                              hipStream_t stream) {
  const float* x    = (const float*)d_in[0];
  const float* w1   = (const float*)d_in[1];
  const float* cw   = (const float*)d_in[2];
  const float* cb   = (const float*)d_in[3];
  const float* alog = (const float*)d_in[4];
  const float* Dp   = (const float*)d_in[5];
  const float* w2   = (const float*)d_in[6];
  const float* dtw  = (const float*)d_in[7];
  const float* dtb  = (const float*)d_in[8];
  const float* w3   = (const float*)d_in[9];
  float* out = (float*)d_out;
  char* ws = (char*)d_ws;

  size_t off = 0;
  auto alloc = [&](size_t bytes) { size_t o = off; off += (bytes + 255) & ~(size_t)255; return o; };
  // xz region is reused: after conv+szT consume it, dtT and ybf overlay it.
  char*           xzr   = ws + alloc((size_t)M_ROWS * 3072 * 4);            // 50.3 MB
  float*          xz    = (float*)xzr;
  float*          dtT   = (float*)xzr;                                      // overlay [1536][4096] f32
  unsigned short* ybf   = (unsigned short*)(xzr + (size_t)DINNER * M_ROWS * 4); // overlay
  float*          xdbl  = (float*)(ws + alloc((size_t)M_ROWS * 128 * 4));
  unsigned short* xbf   = (unsigned short*)(ws + alloc((size_t)M_ROWS * DMODEL * 2));
  unsigned short* w1bf  = (unsigned short*)(ws + alloc((size_t)2 * DINNER * DMODEL * 2));
  unsigned short* w2bf  = (unsigned short*)(ws + alloc((size_t)128 * DINNER * 2));
  unsigned short* w3bf  = (unsigned short*)(ws + alloc((size_t)DMODEL * DINNER * 2));
  unsigned short* dtlbf = (unsigned short*)(ws + alloc((size_t)M_ROWS * 64 * 2));
  unsigned short* dtwbf = (unsigned short*)(ws + alloc((size_t)DINNER * 64 * 2));
  unsigned short* xcbf  = (unsigned short*)(ws + alloc((size_t)M_ROWS * DINNER * 2));
  unsigned short* xcT   = (unsigned short*)(ws + alloc((size_t)DINNER * M_ROWS * 2));
  unsigned short* szbf  = (unsigned short*)(ws + alloc((size_t)DINNER * M_ROWS * 2));
  float*          BCt   = (float*)(ws + alloc((size_t)B_SZ * 32 * L_SEQ * 4));

  // 1. cast inputs/weights to bf16
  cast_all_kernel<<<27264, 256, 0, stream>>>(x, w1, w2, w3, dtw, xbf, w1bf, w2bf, w3bf, dtwbf);
  // 2. xz = x @ W_in^T  [4096 x 3072]
  gemm_bt<0><<<dim3(32, 24), 256, 0, stream>>>(xbf, w1bf, xz, DMODEL, 3072, nullptr);
  // 3. depthwise conv + SiLU -> xc (bf16, row-major)
  conv_silu_kernel<<<24576, 256, 0, stream>>>(xz, cw, cb, xcbf);
  // 4. szT = silu(z)^T (bf16)  [consumes xz z-half; xz dead after this]
  transpose_silu<<<dim3(64, 24), 256, 0, stream>>>(xz, szbf);
  // 5. xcT = xc^T (bf16)
  transpose_bf16<<<dim3(64, 24), 256, 0, stream>>>(xcbf, xcT);
  // 6. x_dbl = xc @ W_x^T  [4096 x 128]
  gemm_bt<0><<<dim3(32, 1), 256, 0, stream>>>(xcbf, w2bf, xdbl, DINNER, 128, nullptr);
  // 7. B/C rows transposed
  bct_kernel<<<128, 256, 0, stream>>>(xdbl, BCt);
  // 8. dt_low -> bf16 padded K=64
  cast_dtlow_kernel<<<1024, 256, 0, stream>>>(xdbl, dtlbf);
  // 9. dtT = softplus(W_dt @ dt_low^T + b)  -> [1536][4096] (transposed GEMM, overlays xz)
  gemm_bt<2><<<dim3(12, 32), 256, 0, stream>>>(dtwbf, dtlbf, dtT, 64, M_ROWS, dtb);
  // 10. single-pass selective scan + fused epilogue -> ybf
  scan_single<<<dim3(384, 2), 64, 0, stream>>>(dtT, xcT, BCt, szbf, alog, Dp, ybf);
  // 11. out = y @ W_out^T  [4096 x 768]
  gemm_bt<0><<<dim3(32, 6), 256, 0, stream>>>(ybf, w3bf, out, DINNER, 768, nullptr);
}

// Round 5
// 347.400 us; speedup vs baseline: 1.1713x; 1.1242x over previous
//
#include <hip/hip_runtime.h>
#include <stdint.h>

#define B_SZ    2
#define L_SEQ   2048
#define DMODEL  768
#define DSTATE  16
#define DINNER  1536
#define DTRANK  48
#define M_ROWS  4096      // B*L
#define NCHUNK  32

typedef __attribute__((ext_vector_type(8))) short bf16x8;
typedef __attribute__((ext_vector_type(4))) float f32x4;
typedef __attribute__((ext_vector_type(4))) unsigned int u32x4;
typedef __attribute__((ext_vector_type(2))) unsigned int u32x2;

__device__ __forceinline__ unsigned short f2bf(float f) {
  unsigned int u = __float_as_uint(f);
  u += 0x7FFFu + ((u >> 16) & 1u);          // RNE
  return (unsigned short)(u >> 16);
}
__device__ __forceinline__ float bf2f(unsigned short h) {
  return __uint_as_float(((unsigned int)h) << 16);
}
__device__ __forceinline__ float fexp(float x) {   // e^x via v_exp_f32
  return __builtin_amdgcn_exp2f(x * 1.44269504088896340736f);
}
__device__ __forceinline__ float sigm(float x) {
  return 1.0f / (1.0f + fexp(-x));
}

template <int CTRL>
__device__ __forceinline__ float dpp_add(float v) {
  int x = __builtin_amdgcn_update_dpp(0, __float_as_int(v), CTRL, 0xF, 0xF, true);
  return v + __int_as_float(x);
}
// sum within aligned quads of lanes; all 4 lanes hold the quad sum
__device__ __forceinline__ float quad_sum(float v) {
  v = dpp_add<0xB1>(v);   // quad_perm [1,0,3,2]
  v = dpp_add<0x4E>(v);   // quad_perm [2,3,0,1]
  return v;
}

// ---------------------------------------------------------------- casts ----
__global__ void cast_all_kernel(const float* __restrict__ x, const float* __restrict__ w1,
                                const float* __restrict__ w2, const float* __restrict__ w3,
                                const float* __restrict__ dtw,
                                unsigned short* __restrict__ xbf, unsigned short* __restrict__ w1bf,
                                unsigned short* __restrict__ w2bf, unsigned short* __restrict__ w3bf,
                                unsigned short* __restrict__ dtwbf) {
  int i = blockIdx.x * 256 + threadIdx.x;
  const int n_x = M_ROWS * DMODEL;
  const int n_w1 = 2 * DINNER * DMODEL;
  const int n_w3 = DMODEL * DINNER;
  const int n_w2 = 128 * DINNER;
  const int n_dtw = DINNER * 64;
  if (i < n_x)  { xbf[i] = f2bf(x[i]); return; }  i -= n_x;
  if (i < n_w1) { w1bf[i] = f2bf(w1[i]); return; } i -= n_w1;
  if (i < n_w3) { w3bf[i] = f2bf(w3[i]); return; } i -= n_w3;
  if (i < n_w2) {
    int row = i / DINNER, col = i - row * DINNER;
    w2bf[i] = (row < (DTRANK + 2 * DSTATE)) ? f2bf(w2[row * DINNER + col]) : (unsigned short)0;
    return;
  }
  i -= n_w2;
  if (i < n_dtw) {
    int row = i >> 6, col = i & 63;
    dtwbf[i] = (col < DTRANK) ? f2bf(dtw[row * DTRANK + col]) : (unsigned short)0;
  }
}

__global__ void cast_dtlow_kernel(const float* __restrict__ xdbl, unsigned short* __restrict__ out) {
  int i = blockIdx.x * 256 + threadIdx.x;   // 4096*64
  int row = i >> 6, col = i & 63;
  out[i] = (col < DTRANK) ? f2bf(xdbl[row * 128 + col]) : (unsigned short)0;
}

// --------------------------------------------------- bf16 MFMA GEMM (B^T) ----
// C[m][n] = sum_k A[m][k]*Bt[n][k]. EPI: 0 plain; 2 softplus(acc + bias[row]).
template <int EPI>
__global__ __launch_bounds__(256, 2) void gemm_bt(
    const unsigned short* __restrict__ A, const unsigned short* __restrict__ Bt,
    float* __restrict__ C, int K, int ldc, const float* __restrict__ bias) {
  __shared__ unsigned short As[128 * 40];
  __shared__ unsigned short Bs[128 * 40];
  const int tid = threadIdx.x;
  const int m0 = blockIdx.x * 128;
  const int n0 = blockIdx.y * 128;
  const int lane = tid & 63;
  const int wave = tid >> 6;
  const int wr = (wave >> 1) * 64, wc = (wave & 1) * 64;
  const int lm = lane & 15, q = lane >> 4;
  const int r = tid >> 2, sg = (tid & 3) * 8;

  f32x4 acc[4][4] = {};

  for (int k0 = 0; k0 < K; k0 += 32) {
    u32x4 a0 = *(const u32x4*)(A + (size_t)(m0 + r) * K + k0 + sg);
    u32x4 a1 = *(const u32x4*)(A + (size_t)(m0 + r + 64) * K + k0 + sg);
    u32x4 b0 = *(const u32x4*)(Bt + (size_t)(n0 + r) * K + k0 + sg);
    u32x4 b1 = *(const u32x4*)(Bt + (size_t)(n0 + r + 64) * K + k0 + sg);
    __syncthreads();
    *(u32x4*)&As[r * 40 + sg] = a0;
    *(u32x4*)&As[(r + 64) * 40 + sg] = a1;
    *(u32x4*)&Bs[r * 40 + sg] = b0;
    *(u32x4*)&Bs[(r + 64) * 40 + sg] = b1;
    __syncthreads();
    bf16x8 af[4], bq[4];
#pragma unroll
    for (int mt = 0; mt < 4; mt++)
      af[mt] = *(const bf16x8*)&As[(wr + mt * 16 + lm) * 40 + q * 8];
#pragma unroll
    for (int nt = 0; nt < 4; nt++)
      bq[nt] = *(const bf16x8*)&Bs[(wc + nt * 16 + lm) * 40 + q * 8];
#pragma unroll
    for (int mt = 0; mt < 4; mt++)
#pragma unroll
      for (int nt = 0; nt < 4; nt++)
        acc[mt][nt] = __builtin_amdgcn_mfma_f32_16x16x32_bf16(af[mt], bq[nt], acc[mt][nt], 0, 0, 0);
  }

#pragma unroll
  for (int mt = 0; mt < 4; mt++) {
    int row0 = m0 + wr + mt * 16 + q * 4;
    float bs4[4];
    if (EPI == 2) {
#pragma unroll
      for (int i = 0; i < 4; i++) bs4[i] = bias[row0 + i];
    }
#pragma unroll
    for (int nt = 0; nt < 4; nt++) {
      int col = n0 + wc + nt * 16 + lm;
#pragma unroll
      for (int i = 0; i < 4; i++) {
        float v = acc[mt][nt][i];
        if (EPI == 2) {                      // softplus(v + bias[row]), stable
          v += bs4[i];
          v = (v > 15.f) ? v : log1pf(fexp(v));
        }
        C[(size_t)(row0 + i) * ldc + col] = v;
      }
    }
  }
}

// ------------------------------------------------- depthwise conv + SiLU ----
__global__ void conv_silu_kernel(const float* __restrict__ xz, const float* __restrict__ cw,
                                 const float* __restrict__ cb, unsigned short* __restrict__ xcbf) {
  int idx = blockIdx.x * 256 + threadIdx.x;
  if (idx >= B_SZ * L_SEQ * DINNER) return;
  int d = idx % DINNER;
  int bl = idx / DINNER;
  int l = bl & (L_SEQ - 1);
  float acc = cb[d];
#pragma unroll
  for (int k = 0; k < 4; k++) {
    int ll = l - 3 + k;
    if (ll >= 0) acc += cw[d * 4 + k] * xz[(size_t)(bl - 3 + k) * 3072 + d];
  }
  xcbf[idx] = f2bf(acc * sigm(acc));
}

// ----------------------------------------------------- transpose kernels ----
__global__ __launch_bounds__(256) void transpose_bf16(const unsigned short* __restrict__ in,
                                                      unsigned short* __restrict__ out) {
  __shared__ unsigned short tl[64 * 80];
  const int r0 = blockIdx.x * 64;
  const int c0 = blockIdx.y * 64;
  const int tid = threadIdx.x;
#pragma unroll
  for (int it = 0; it < 2; it++) {
    int idx = tid + it * 256;
    int rr = idx >> 3, cs = idx & 7;
    u32x4 v = *(const u32x4*)(in + (size_t)(r0 + rr) * DINNER + c0 + cs * 8);
    *(u32x4*)&tl[rr * 80 + cs * 8] = v;
  }
  __syncthreads();
#pragma unroll
  for (int it = 0; it < 2; it++) {
    int idx = tid + it * 256;
    int cc = idx & 63, rs = idx >> 6;
    unsigned int w[4];
#pragma unroll
    for (int p = 0; p < 4; p++) {
      unsigned int lo = tl[(rs * 8 + 2 * p) * 80 + cc];
      unsigned int hi = tl[(rs * 8 + 2 * p + 1) * 80 + cc];
      w[p] = lo | (hi << 16);
    }
    *(u32x4*)(out + (size_t)(c0 + cc) * M_ROWS + r0 + rs * 8) = *(u32x4*)w;
  }
}

__global__ __launch_bounds__(256) void transpose_silu(const float* __restrict__ xz,
                                                      unsigned short* __restrict__ out) {
  __shared__ float tl[64 * 68];
  const int r0 = blockIdx.x * 64;
  const int c0 = blockIdx.y * 64;
  const int tid = threadIdx.x;
#pragma unroll
  for (int it = 0; it < 4; it++) {
    int idx = tid + it * 256;
    int rr = idx >> 4, cs = idx & 15;
    f32x4 v = *(const f32x4*)(xz + (size_t)(r0 + rr) * 3072 + DINNER + c0 + cs * 4);
#pragma unroll
    for (int p = 0; p < 4; p++) v[p] = v[p] * sigm(v[p]);
    *(f32x4*)&tl[rr * 68 + cs * 4] = v;
  }
  __syncthreads();
#pragma unroll
  for (int it = 0; it < 2; it++) {
    int idx = tid + it * 256;
    int cc = idx & 63, rs = idx >> 6;
    unsigned int w[4];
#pragma unroll
    for (int p = 0; p < 4; p++) {
      unsigned int lo = f2bf(tl[(rs * 8 + 2 * p) * 68 + cc]);
      unsigned int hi = f2bf(tl[(rs * 8 + 2 * p + 1) * 68 + cc]);
      w[p] = lo | (hi << 16);
    }
    *(u32x4*)(out + (size_t)(c0 + cc) * M_ROWS + r0 + rs * 8) = *(u32x4*)w;
  }
}

// x_dbl cols 48..79 -> BCt[b][j][l]  (j<16: B_s, j>=16: C_s)
__global__ void bct_kernel(const float* __restrict__ xdbl, float* __restrict__ BCt) {
  int t = blockIdx.x * 256 + threadIdx.x;   // 32768 total
  int l4 = t & 511;
  int j  = (t >> 9) & 31;
  int b  = (t >> 14) & 1;
  f32x4 o;
#pragma unroll
  for (int i = 0; i < 4; i++)
    o[i] = xdbl[((size_t)b * L_SEQ + l4 * 4 + i) * 128 + DTRANK + j];
  *(f32x4*)(BCt + ((size_t)b * 32 + j) * L_SEQ + l4 * 4) = o;
}

// -------------------------------------------- single-pass selective scan ----
// One wave per (4-channel group, batch). LDS double-buffered 64-step
// superchunks: coalesced global loads into regs for c+2, regs->LDS for c+1,
// consume c from LDS (never waits on vmcnt). Wave-private LDS, no barriers.
struct SC { f32x4 dt; u32x2 xc, sz; f32x4 B[4], C[4]; };  // 40 VGPRs

__device__ __forceinline__ void load_sc(SC& R, int lane,
    const float* __restrict__ dtbase, const unsigned short* __restrict__ xcbase,
    const unsigned short* __restrict__ szbase, const float* __restrict__ Bbase,
    const float* __restrict__ Cbase, int l0) {
  const int ch = lane >> 4, li = lane & 15;
  const int s4 = lane >> 2, lj = lane & 3;
  R.dt = *(const f32x4*)(dtbase + (size_t)ch * M_ROWS + l0 + li * 4);
  R.xc = *(const u32x2*)(xcbase + (size_t)ch * M_ROWS + l0 + li * 4);
  R.sz = *(const u32x2*)(szbase + (size_t)ch * M_ROWS + l0 + li * 4);
#pragma unroll
  for (int j = 0; j < 4; j++) {
    R.B[j] = *(const f32x4*)(Bbase + (size_t)s4 * L_SEQ + l0 + lj * 16 + j * 4);
    R.C[j] = *(const f32x4*)(Cbase + (size_t)s4 * L_SEQ + l0 + lj * 16 + j * 4);
  }
}

__device__ __forceinline__ void store_sc(float* dtS, float* dtxS, unsigned int* xcR,
                                         unsigned int* szR, float* BS, float* CS,
                                         const SC& R, int lane) {
  const int ch = lane >> 4, li = lane & 15;
  const int s4 = lane >> 2, lj = lane & 3;
  f32x4 xf, dtx;
  xf[0] = __uint_as_float(R.xc[0] << 16);
  xf[1] = __uint_as_float(R.xc[0] & 0xFFFF0000u);
  xf[2] = __uint_as_float(R.xc[1] << 16);
  xf[3] = __uint_as_float(R.xc[1] & 0xFFFF0000u);
  dtx = R.dt * xf;                        // dt*xc precompute (saves 2 VALU/step)
  *(f32x4*)&dtS[ch * 68 + li * 4] = R.dt;
  *(f32x4*)&dtxS[ch * 68 + li * 4] = dtx;
  *(u32x2*)&xcR[ch * 34 + li * 2] = R.xc;
  *(u32x2*)&szR[ch * 34 + li * 2] = R.sz;
#pragma unroll
  for (int j = 0; j < 4; j++) {
    *(f32x4*)&BS[s4 * 68 + lj * 16 + j * 4] = R.B[j];
    *(f32x4*)&CS[s4 * 68 + lj * 16 + j * 4] = R.C[j];
  }
}

__global__ __launch_bounds__(64, 1) void scan_single(
    const float* __restrict__ dtT, const unsigned short* __restrict__ xcT,
    const float* __restrict__ BCt, const unsigned short* __restrict__ szT,
    const float* __restrict__ A_log, const float* __restrict__ Dp,
    unsigned short* __restrict__ ybf) {
  __shared__ float dtS[2][4 * 68];
  __shared__ float dtxS[2][4 * 68];
  __shared__ unsigned int xcR[2][4 * 34];
  __shared__ unsigned int szR[2][4 * 34];
  __shared__ float BS[2][16 * 68];
  __shared__ float CS[2][16 * 68];
  __shared__ float ysh[16 * 68];
  const int lane = threadIdx.x;
  const int s = lane & 15, dl = lane >> 4;
  const int d0 = blockIdx.x * 4;
  const int d = d0 + dl;
  const int b = blockIdx.y;
  const size_t rbase = (size_t)b * L_SEQ;
  const float a2 = -fexp(A_log[d * 16 + s]) * 1.44269504f;  // A*log2(e)
  const float dpv = Dp[d];
  const float* dtbase = dtT + (size_t)d0 * M_ROWS + rbase;
  const unsigned short* xcbase = xcT + (size_t)d0 * M_ROWS + rbase;
  const unsigned short* szbase = szT + (size_t)d0 * M_ROWS + rbase;
  const float* Bbase = BCt + (size_t)b * 32 * L_SEQ;
  const float* Cbase = Bbase + 16 * L_SEQ;
  float* ywp = &ysh[(dl * 4 + (s >> 2)) * 68 + (s & 3)];
  const bool sb0 = (s & 1) != 0, sb1 = (s & 2) != 0;
  float h = 0.f;

  SC R;
  load_sc(R, lane, dtbase, xcbase, szbase, Bbase, Cbase, 0);
  store_sc(dtS[0], dtxS[0], xcR[0], szR[0], BS[0], CS[0], R, lane);
  load_sc(R, lane, dtbase, xcbase, szbase, Bbase, Cbase, 64);

#pragma unroll 1
  for (int c = 0; c < NCHUNK; c++) {
    const int p = c & 1;
    const float* dtP = dtS[p];
    const float* dtxP = dtxS[p];
    const float* BP = BS[p];
    const float* CP = CS[p];
#pragma unroll
    for (int g = 0; g < 8; g++) {
      const int l0 = g * 8;
      f32x4 dta = *(const f32x4*)&dtP[dl * 68 + l0];
      f32x4 dtb = *(const f32x4*)&dtP[dl * 68 + l0 + 4];
      f32x4 xa  = *(const f32x4*)&dtxP[dl * 68 + l0];
      f32x4 xb  = *(const f32x4*)&dtxP[dl * 68 + l0 + 4];
      f32x4 Ba  = *(const f32x4*)&BP[s * 68 + l0];
      f32x4 Bb  = *(const f32x4*)&BP[s * 68 + l0 + 4];
      f32x4 Ca  = *(const f32x4*)&CP[s * 68 + l0];
      f32x4 Cb  = *(const f32x4*)&CP[s * 68 + l0 + 4];
      float p8[8];
#pragma unroll
      for (int j = 0; j < 8; j++) {
        float dtj = (j < 4) ? dta[j] : dtb[j - 4];
        float dxj = (j < 4) ? xa[j]  : xb[j - 4];
        float Bj  = (j < 4) ? Ba[j]  : Bb[j - 4];
        float Cj  = (j < 4) ? Ca[j]  : Cb[j - 4];
        float a = __builtin_amdgcn_exp2f(dtj * a2);
        h = a * h + dxj * Bj;
        p8[j] = h * Cj;
      }
#pragma unroll
      for (int half = 0; half < 2; half++) {
        float q0 = quad_sum(p8[half * 4 + 0]);
        float q1 = quad_sum(p8[half * 4 + 1]);
        float q2 = quad_sum(p8[half * 4 + 2]);
        float q3 = quad_sum(p8[half * 4 + 3]);
        float v01 = sb0 ? q1 : q0;
        float v23 = sb0 ? q3 : q2;
        ywp[g * 8 + half * 4] = sb1 ? v23 : v01;   // 1 ds_write_b32, 2-way banks
      }
    }
    // ---- chunk epilogue: lane covers (ch=dl, l = s*4 .. s*4+3), all from LDS ----
    {
      f32x4 y0 = *(const f32x4*)&ysh[(dl * 4 + 0) * 68 + s * 4];
      f32x4 y1 = *(const f32x4*)&ysh[(dl * 4 + 1) * 68 + s * 4];
      f32x4 y2 = *(const f32x4*)&ysh[(dl * 4 + 2) * 68 + s * 4];
      f32x4 y3 = *(const f32x4*)&ysh[(dl * 4 + 3) * 68 + s * 4];
      f32x4 ys = y0 + y1 + y2 + y3;
      u32x2 xcu = *(const u32x2*)&xcR[p][dl * 34 + s * 2];
      u32x2 szu = *(const u32x2*)&szR[p][dl * 34 + s * 2];
      float xcf[4] = {__uint_as_float(xcu[0] << 16), __uint_as_float(xcu[0] & 0xFFFF0000u),
                      __uint_as_float(xcu[1] << 16), __uint_as_float(xcu[1] & 0xFFFF0000u)};
      float szf[4] = {__uint_as_float(szu[0] << 16), __uint_as_float(szu[0] & 0xFFFF0000u),
                      __uint_as_float(szu[1] << 16), __uint_as_float(szu[1] & 0xFFFF0000u)};
      size_t rr0 = rbase + c * 64 + s * 4;
#pragma unroll
      for (int i = 0; i < 4; i++) {
        float yv = ys[i] + xcf[i] * dpv;
        ybf[(rr0 + i) * DINNER + d] = f2bf(yv * szf[i]);
      }
    }
    if (c < NCHUNK - 1) {
      store_sc(dtS[p ^ 1], dtxS[p ^ 1], xcR[p ^ 1], szR[p ^ 1], BS[p ^ 1], CS[p ^ 1], R, lane);
      if (c < NCHUNK - 2)
        load_sc(R, lane, dtbase, xcbase, szbase, Bbase, Cbase, (c + 2) * 64);
    }
  }
}

// -------------------------------------------------------------- launcher ----
extern "C" void kernel_launch(void* const* d_in, const int* in_sizes, int n_in,
                              void* d_out, int out_size, void* d_ws, size_t ws_size,
                              hipStream_t stream) {
  const float* x    = (const float*)d_in[0];
  const float* w1   = (const float*)d_in[1];
  const float* cw   = (const float*)d_in[2];
  const float* cb   = (const float*)d_in[3];
  const float* alog = (const float*)d_in[4];
  const float* Dp   = (const float*)d_in[5];
  const float* w2   = (const float*)d_in[6];
  const float* dtw  = (const float*)d_in[7];
  const float* dtb  = (const float*)d_in[8];
  const float* w3   = (const float*)d_in[9];
  float* out = (float*)d_out;
  char* ws = (char*)d_ws;

  size_t off = 0;
  auto alloc = [&](size_t bytes) { size_t o = off; off += (bytes + 255) & ~(size_t)255; return o; };
  // xz region is reused: after conv+szT consume it, dtT and ybf overlay it.
  char*           xzr   = ws + alloc((size_t)M_ROWS * 3072 * 4);            // 50.3 MB
  float*          xz    = (float*)xzr;
  float*          dtT   = (float*)xzr;                                      // overlay [1536][4096] f32
  unsigned short* ybf   = (unsigned short*)(xzr + (size_t)DINNER * M_ROWS * 4); // overlay
  float*          xdbl  = (float*)(ws + alloc((size_t)M_ROWS * 128 * 4));
  unsigned short* xbf   = (unsigned short*)(ws + alloc((size_t)M_ROWS * DMODEL * 2));
  unsigned short* w1bf  = (unsigned short*)(ws + alloc((size_t)2 * DINNER * DMODEL * 2));
  unsigned short* w2bf  = (unsigned short*)(ws + alloc((size_t)128 * DINNER * 2));
  unsigned short* w3bf  = (unsigned short*)(ws + alloc((size_t)DMODEL * DINNER * 2));
  unsigned short* dtlbf = (unsigned short*)(ws + alloc((size_t)M_ROWS * 64 * 2));
  unsigned short* dtwbf = (unsigned short*)(ws + alloc((size_t)DINNER * 64 * 2));
  unsigned short* xcbf  = (unsigned short*)(ws + alloc((size_t)M_ROWS * DINNER * 2));
  unsigned short* xcT   = (unsigned short*)(ws + alloc((size_t)DINNER * M_ROWS * 2));
  unsigned short* szbf  = (unsigned short*)(ws + alloc((size_t)DINNER * M_ROWS * 2));
  float*          BCt   = (float*)(ws + alloc((size_t)B_SZ * 32 * L_SEQ * 4));

  // 1. cast inputs/weights to bf16
  cast_all_kernel<<<27264, 256, 0, stream>>>(x, w1, w2, w3, dtw, xbf, w1bf, w2bf, w3bf, dtwbf);
  // 2. xz = x @ W_in^T  [4096 x 3072]
  gemm_bt<0><<<dim3(32, 24), 256, 0, stream>>>(xbf, w1bf, xz, DMODEL, 3072, nullptr);
  // 3. depthwise conv + SiLU -> xc (bf16, row-major)
  conv_silu_kernel<<<24576, 256, 0, stream>>>(xz, cw, cb, xcbf);
  // 4. szT = silu(z)^T (bf16)  [consumes xz z-half; xz dead after this]
  transpose_silu<<<dim3(64, 24), 256, 0, stream>>>(xz, szbf);
  // 5. xcT = xc^T (bf16)
  transpose_bf16<<<dim3(64, 24), 256, 0, stream>>>(xcbf, xcT);
  // 6. x_dbl = xc @ W_x^T  [4096 x 128]
  gemm_bt<0><<<dim3(32, 1), 256, 0, stream>>>(xcbf, w2bf, xdbl, DINNER, 128, nullptr);
  // 7. B/C rows transposed
  bct_kernel<<<128, 256, 0, stream>>>(xdbl, BCt);
  // 8. dt_low -> bf16 padded K=64
  cast_dtlow_kernel<<<1024, 256, 0, stream>>>(xdbl, dtlbf);
  // 9. dtT = softplus(W_dt @ dt_low^T + b)  -> [1536][4096] (transposed GEMM, overlays xz)
  gemm_bt<2><<<dim3(12, 32), 256, 0, stream>>>(dtwbf, dtlbf, dtT, 64, M_ROWS, dtb);
  // 10. single-pass selective scan + fused epilogue -> ybf
  scan_single<<<dim3(384, 2), 64, 0, stream>>>(dtT, xcT, BCt, szbf, alog, Dp, ybf);
  // 11. out = y @ W_out^T  [4096 x 768]
  gemm_bt<0><<<dim3(32, 6), 256, 0, stream>>>(ybf, w3bf, out, DINNER, 768, nullptr);
}

// Round 6
// 332.519 us; speedup vs baseline: 1.2237x; 1.0448x over previous
//
#include <hip/hip_runtime.h>
#include <stdint.h>

#define B_SZ    2
#define L_SEQ   2048
#define DMODEL  768
#define DSTATE  16
#define DINNER  1536
#define DTRANK  48
#define M_ROWS  4096      // B*L
#define NSEG    4
#define SEGL    512
#define NSC     16        // superchunks per segment
#define SCL     32        // steps per superchunk

typedef __attribute__((ext_vector_type(8))) short bf16x8;
typedef __attribute__((ext_vector_type(4))) float f32x4;
typedef __attribute__((ext_vector_type(2))) float f32x2;
typedef __attribute__((ext_vector_type(4))) unsigned int u32x4;
typedef __attribute__((ext_vector_type(2))) unsigned int u32x2;

__device__ __forceinline__ unsigned short f2bf(float f) {
  unsigned int u = __float_as_uint(f);
  u += 0x7FFFu + ((u >> 16) & 1u);          // RNE
  return (unsigned short)(u >> 16);
}
__device__ __forceinline__ unsigned int pack2bf(float a, float b) {
  return (unsigned int)f2bf(a) | ((unsigned int)f2bf(b) << 16);
}
__device__ __forceinline__ float bf2f(unsigned short h) {
  return __uint_as_float(((unsigned int)h) << 16);
}
__device__ __forceinline__ float fexp(float x) {
  return __builtin_amdgcn_exp2f(x * 1.44269504088896340736f);
}
__device__ __forceinline__ float sigm(float x) {
  return 1.0f / (1.0f + fexp(-x));
}

template <int CTRL>
__device__ __forceinline__ float dpp_add(float v) {
  int x = __builtin_amdgcn_update_dpp(0, __float_as_int(v), CTRL, 0xF, 0xF, true);
  return v + __int_as_float(x);
}
__device__ __forceinline__ float quad_sum(float v) {
  v = dpp_add<0xB1>(v);   // quad_perm [1,0,3,2]
  v = dpp_add<0x4E>(v);   // quad_perm [2,3,0,1]
  return v;
}
__device__ __forceinline__ float row16_sum(float v) {
  v = dpp_add<0xB1>(v);
  v = dpp_add<0x4E>(v);
  v = dpp_add<0x124>(v);  // row_ror:4
  v = dpp_add<0x128>(v);  // row_ror:8
  return v;
}

// ---------------------------------------------------------------- casts ----
__global__ void cast_all_kernel(const float* __restrict__ x, const float* __restrict__ w1,
                                const float* __restrict__ w2, const float* __restrict__ w3,
                                const float* __restrict__ dtw,
                                unsigned short* __restrict__ xbf, unsigned short* __restrict__ w1bf,
                                unsigned short* __restrict__ w2bf, unsigned short* __restrict__ w3bf,
                                unsigned short* __restrict__ dtwbf) {
  int i = blockIdx.x * 256 + threadIdx.x;
  const int n_x = M_ROWS * DMODEL;
  const int n_w1 = 2 * DINNER * DMODEL;
  const int n_w3 = DMODEL * DINNER;
  const int n_w2 = 128 * DINNER;
  const int n_dtw = DINNER * 64;
  if (i < n_x)  { xbf[i] = f2bf(x[i]); return; }  i -= n_x;
  if (i < n_w1) { w1bf[i] = f2bf(w1[i]); return; } i -= n_w1;
  if (i < n_w3) { w3bf[i] = f2bf(w3[i]); return; } i -= n_w3;
  if (i < n_w2) {
    int row = i / DINNER, col = i - row * DINNER;
    w2bf[i] = (row < (DTRANK + 2 * DSTATE)) ? f2bf(w2[row * DINNER + col]) : (unsigned short)0;
    return;
  }
  i -= n_w2;
  if (i < n_dtw) {
    int row = i >> 6, col = i & 63;
    dtwbf[i] = (col < DTRANK) ? f2bf(dtw[row * DTRANK + col]) : (unsigned short)0;
  }
}

// merged: cast dt_low (padded K=64) + B/C transpose
__global__ void xdbl_pack_kernel(const float* __restrict__ xdbl,
                                 unsigned short* __restrict__ dtlbf,
                                 float* __restrict__ BCt) {
  int i = blockIdx.x * 256 + threadIdx.x;
  const int n_dtl = M_ROWS * 64;            // 262144
  if (i < n_dtl) {
    int row = i >> 6, col = i & 63;
    dtlbf[i] = (col < DTRANK) ? f2bf(xdbl[row * 128 + col]) : (unsigned short)0;
    return;
  }
  i -= n_dtl;                               // 32768 entries
  int l4 = i & 511;
  int j  = (i >> 9) & 31;
  int b  = (i >> 14) & 1;
  f32x4 o;
#pragma unroll
  for (int k = 0; k < 4; k++)
    o[k] = xdbl[((size_t)b * L_SEQ + l4 * 4 + k) * 128 + DTRANK + j];
  *(f32x4*)(BCt + ((size_t)b * 32 + j) * L_SEQ + l4 * 4) = o;
}

// --------------------------------------------------- bf16 MFMA GEMM (B^T) ----
// C[m][n] = sum_{k in [bz*KS, bz*KS+KS)} A[m][k]*Bt[n][k]; K = row stride.
// EPI: 0 plain store; 2 softplus(acc+bias[row]); 3 atomicAdd (split-K).
template <int EPI>
__global__ __launch_bounds__(256, 2) void gemm_bt(
    const unsigned short* __restrict__ A, const unsigned short* __restrict__ Bt,
    float* __restrict__ C, int K, int KS, int ldc, const float* __restrict__ bias) {
  __shared__ unsigned short As[128 * 40];
  __shared__ unsigned short Bs[128 * 40];
  const int tid = threadIdx.x;
  const int m0 = blockIdx.x * 128;
  const int n0 = blockIdx.y * 128;
  const int ks = blockIdx.z * KS, ke = ks + KS;
  const int lane = tid & 63;
  const int wave = tid >> 6;
  const int wr = (wave >> 1) * 64, wc = (wave & 1) * 64;
  const int lm = lane & 15, q = lane >> 4;
  const int r = tid >> 2, sg = (tid & 3) * 8;

  f32x4 acc[4][4] = {};

  for (int k0 = ks; k0 < ke; k0 += 32) {
    u32x4 a0 = *(const u32x4*)(A + (size_t)(m0 + r) * K + k0 + sg);
    u32x4 a1 = *(const u32x4*)(A + (size_t)(m0 + r + 64) * K + k0 + sg);
    u32x4 b0 = *(const u32x4*)(Bt + (size_t)(n0 + r) * K + k0 + sg);
    u32x4 b1 = *(const u32x4*)(Bt + (size_t)(n0 + r + 64) * K + k0 + sg);
    __syncthreads();
    *(u32x4*)&As[r * 40 + sg] = a0;
    *(u32x4*)&As[(r + 64) * 40 + sg] = a1;
    *(u32x4*)&Bs[r * 40 + sg] = b0;
    *(u32x4*)&Bs[(r + 64) * 40 + sg] = b1;
    __syncthreads();
    bf16x8 af[4], bq[4];
#pragma unroll
    for (int mt = 0; mt < 4; mt++)
      af[mt] = *(const bf16x8*)&As[(wr + mt * 16 + lm) * 40 + q * 8];
#pragma unroll
    for (int nt = 0; nt < 4; nt++)
      bq[nt] = *(const bf16x8*)&Bs[(wc + nt * 16 + lm) * 40 + q * 8];
#pragma unroll
    for (int mt = 0; mt < 4; mt++)
#pragma unroll
      for (int nt = 0; nt < 4; nt++)
        acc[mt][nt] = __builtin_amdgcn_mfma_f32_16x16x32_bf16(af[mt], bq[nt], acc[mt][nt], 0, 0, 0);
  }

#pragma unroll
  for (int mt = 0; mt < 4; mt++) {
    int row0 = m0 + wr + mt * 16 + q * 4;
    float bs4[4];
    if (EPI == 2) {
#pragma unroll
      for (int i = 0; i < 4; i++) bs4[i] = bias[row0 + i];
    }
#pragma unroll
    for (int nt = 0; nt < 4; nt++) {
      int col = n0 + wc + nt * 16 + lm;
#pragma unroll
      for (int i = 0; i < 4; i++) {
        float v = acc[mt][nt][i];
        if (EPI == 2) {
          v += bs4[i];
          v = (v > 15.f) ? v : log1pf(fexp(v));
        }
        if (EPI == 3) atomicAdd(&C[(size_t)(row0 + i) * ldc + col], v);
        else          C[(size_t)(row0 + i) * ldc + col] = v;
      }
    }
  }
}

// ------------------- fused depthwise conv + SiLU -> xcbf (row) + xcT (col) ----
__global__ __launch_bounds__(256) void conv_silu_t(const float* __restrict__ xz,
                                                   const float* __restrict__ cw,
                                                   const float* __restrict__ cb,
                                                   unsigned short* __restrict__ xcbf,
                                                   unsigned short* __restrict__ xcT) {
  __shared__ float tl[67 * 68];
  __shared__ unsigned short xs[64 * 80];
  __shared__ float cws[64 * 4];
  __shared__ float cbs[64];
  const int r0 = blockIdx.x * 64;     // global row b*L+l
  const int c0 = blockIdx.y * 64;     // channel d
  const int t = threadIdx.x;
  cws[t] = cw[(c0 + (t >> 2)) * 4 + (t & 3)];
  if (t < 64) cbs[t] = cb[c0 + t];
  const bool lowedge = (r0 & (L_SEQ - 1)) == 0;
#pragma unroll
  for (int it = 0; it < 5; it++) {
    int idx = t + it * 256;
    int rr = idx >> 4;
    int cs4 = (idx & 15) * 4;
    if (rr < 67) {
      f32x4 v;
      if (lowedge && rr < 3) v = (f32x4){0.f, 0.f, 0.f, 0.f};
      else v = *(const f32x4*)(xz + (size_t)(r0 + rr - 3) * 3072 + c0 + cs4);
      *(f32x4*)&tl[rr * 68 + cs4] = v;
    }
  }
  __syncthreads();
  const int cs = (t & 15) * 4;
  f32x4 w0, w1, w2, w3, cbv;
#pragma unroll
  for (int j = 0; j < 4; j++) {
    w0[j] = cws[(cs + j) * 4 + 0];
    w1[j] = cws[(cs + j) * 4 + 1];
    w2[j] = cws[(cs + j) * 4 + 2];
    w3[j] = cws[(cs + j) * 4 + 3];
    cbv[j] = cbs[cs + j];
  }
#pragma unroll
  for (int it = 0; it < 4; it++) {
    int r = (t >> 4) + it * 16;
    f32x4 t0 = *(const f32x4*)&tl[(r + 0) * 68 + cs];
    f32x4 t1 = *(const f32x4*)&tl[(r + 1) * 68 + cs];
    f32x4 t2 = *(const f32x4*)&tl[(r + 2) * 68 + cs];
    f32x4 t3 = *(const f32x4*)&tl[(r + 3) * 68 + cs];
    f32x4 acc = cbv + w0 * t0 + w1 * t1 + w2 * t2 + w3 * t3;
#pragma unroll
    for (int j = 0; j < 4; j++) acc[j] = acc[j] * sigm(acc[j]);
    u32x2 pk;
    pk[0] = pack2bf(acc[0], acc[1]);
    pk[1] = pack2bf(acc[2], acc[3]);
    *(u32x2*)(xcbf + (size_t)(r0 + r) * DINNER + c0 + cs) = pk;
    *(u32x2*)&xs[r * 80 + cs] = pk;
  }
  __syncthreads();
#pragma unroll
  for (int it = 0; it < 2; it++) {
    int idx = t + it * 256;
    int cc = idx & 63, rs = idx >> 6;
    unsigned int w[4];
#pragma unroll
    for (int p = 0; p < 4; p++) {
      unsigned int lo = xs[(rs * 8 + 2 * p) * 80 + cc];
      unsigned int hi = xs[(rs * 8 + 2 * p + 1) * 80 + cc];
      w[p] = lo | (hi << 16);
    }
    *(u32x4*)(xcT + (size_t)(c0 + cc) * M_ROWS + r0 + rs * 8) = *(u32x4*)w;
  }
}

// --------------------------------------- z-half silu + transpose -> szT ----
__global__ __launch_bounds__(256) void transpose_silu(const float* __restrict__ xz,
                                                      unsigned short* __restrict__ out) {
  __shared__ float tl[64 * 68];
  const int r0 = blockIdx.x * 64;
  const int c0 = blockIdx.y * 64;
  const int tid = threadIdx.x;
#pragma unroll
  for (int it = 0; it < 4; it++) {
    int idx = tid + it * 256;
    int rr = idx >> 4, cs = idx & 15;
    f32x4 v = *(const f32x4*)(xz + (size_t)(r0 + rr) * 3072 + DINNER + c0 + cs * 4);
#pragma unroll
    for (int p = 0; p < 4; p++) v[p] = v[p] * sigm(v[p]);
    *(f32x4*)&tl[rr * 68 + cs * 4] = v;
  }
  __syncthreads();
#pragma unroll
  for (int it = 0; it < 2; it++) {
    int idx = tid + it * 256;
    int cc = idx & 63, rs = idx >> 6;
    unsigned int w[4];
#pragma unroll
    for (int p = 0; p < 4; p++)
      w[p] = pack2bf(tl[(rs * 8 + 2 * p) * 68 + cc], tl[(rs * 8 + 2 * p + 1) * 68 + cc]);
    *(u32x4*)(out + (size_t)(c0 + cc) * M_ROWS + r0 + rs * 8) = *(u32x4*)w;
  }
}

// ------------------------------------------------ segmented selective scan ----
// One wave per (4-channel group, batch, 512-step segment). LDS double-buffered
// 32-step superchunks (coalesced global->reg->LDS, consume from LDS).
// FULL=0: phase1 (emit P=exp2(a2*sum dt), h_local).  FULL=1: phase3 (h_in from
// HIN, full y + fused epilogue).
struct SC32 { f32x2 dt; unsigned int xc, sz; f32x4 B0, B1, C0, C1; };

template <int FULL>
__global__ __launch_bounds__(64) void scan_seg(
    const float* __restrict__ dtT, const unsigned short* __restrict__ xcT,
    const float* __restrict__ BCt, const unsigned short* __restrict__ szT,
    const float* __restrict__ A_log, const float* __restrict__ Dp,
    const float* __restrict__ HIN, float* __restrict__ P, float* __restrict__ HL,
    unsigned short* __restrict__ ybf) {
  __shared__ float dtS[2][4 * 36];
  __shared__ float dtxS[2][4 * 36];
  __shared__ float BS[2][16 * 36];
  __shared__ float CS[2][16 * 36];
  __shared__ unsigned int xcR[2][4 * 18];
  __shared__ unsigned int szR[2][4 * 18];
  __shared__ float ysh[16 * 36];
  const int lane = threadIdx.x;
  const int s = lane & 15, dl = lane >> 4;
  const int d0 = blockIdx.x * 4;
  const int d = d0 + dl;
  const int b = blockIdx.y;
  const int seg = blockIdx.z;
  const int lseg = seg * SEGL;
  const size_t rbase = (size_t)b * L_SEQ + lseg;
  const float a2 = -fexp(A_log[d * 16 + s]) * 1.44269504f;
  const float dpv = Dp[d];
  const float* dtbase = dtT + (size_t)d0 * M_ROWS + rbase;
  const unsigned short* xcbase = xcT + (size_t)d0 * M_ROWS + rbase;
  const unsigned short* szbase = szT + (size_t)d0 * M_ROWS + rbase;
  const float* Bbase = BCt + (size_t)b * 32 * L_SEQ + lseg;
  const float* Cbase = Bbase + 16 * L_SEQ;
  // staging lane mapping
  const int ch = lane >> 4, li = lane & 15;     // dt/xc/sz
  const int s4 = lane >> 2, lj = lane & 3;      // B/C
  float* ywp = &ysh[(dl * 4 + (s >> 2)) * 36 + (s & 3)];
  const bool sb0 = (s & 1) != 0, sb1 = (s & 2) != 0;
  float h = 0.f, sdt = 0.f;
  size_t o = (((size_t)seg * B_SZ + b) * DINNER + d) * 16 + s;
  if (FULL) h = HIN[o];

  auto load32 = [&](SC32& R, int l0) {
    R.dt = *(const f32x2*)(dtbase + (size_t)ch * M_ROWS + l0 + li * 2);
    R.xc = *(const unsigned int*)(xcbase + (size_t)ch * M_ROWS + l0 + li * 2);
    if (FULL) R.sz = *(const unsigned int*)(szbase + (size_t)ch * M_ROWS + l0 + li * 2);
    R.B0 = *(const f32x4*)(Bbase + (size_t)s4 * L_SEQ + l0 + lj * 8);
    R.B1 = *(const f32x4*)(Bbase + (size_t)s4 * L_SEQ + l0 + lj * 8 + 4);
    if (FULL) {
      R.C0 = *(const f32x4*)(Cbase + (size_t)s4 * L_SEQ + l0 + lj * 8);
      R.C1 = *(const f32x4*)(Cbase + (size_t)s4 * L_SEQ + l0 + lj * 8 + 4);
    }
  };
  auto store32 = [&](int p, const SC32& R) {
    if (!FULL) sdt += R.dt[0] + R.dt[1];
    f32x2 xf, dtx;
    xf[0] = __uint_as_float(R.xc << 16);
    xf[1] = __uint_as_float(R.xc & 0xFFFF0000u);
    dtx = R.dt * xf;
    *(f32x2*)&dtS[p][ch * 36 + li * 2] = R.dt;
    *(f32x2*)&dtxS[p][ch * 36 + li * 2] = dtx;
    if (FULL) {
      xcR[p][ch * 18 + li] = R.xc;
      szR[p][ch * 18 + li] = R.sz;
    }
    *(f32x4*)&BS[p][s4 * 36 + lj * 8] = R.B0;
    *(f32x4*)&BS[p][s4 * 36 + lj * 8 + 4] = R.B1;
    if (FULL) {
      *(f32x4*)&CS[p][s4 * 36 + lj * 8] = R.C0;
      *(f32x4*)&CS[p][s4 * 36 + lj * 8 + 4] = R.C1;
    }
  };

  SC32 R;
  load32(R, 0);
  store32(0, R);
  load32(R, SCL);

#pragma unroll 1
  for (int c = 0; c < NSC; c++) {
    const int p = c & 1;
#pragma unroll
    for (int g = 0; g < 4; g++) {
      const int l0g = g * 8;
      f32x4 dta = *(const f32x4*)&dtS[p][dl * 36 + l0g];
      f32x4 dtb = *(const f32x4*)&dtS[p][dl * 36 + l0g + 4];
      f32x4 xa  = *(const f32x4*)&dtxS[p][dl * 36 + l0g];
      f32x4 xb  = *(const f32x4*)&dtxS[p][dl * 36 + l0g + 4];
      f32x4 Ba  = *(const f32x4*)&BS[p][s * 36 + l0g];
      f32x4 Bb  = *(const f32x4*)&BS[p][s * 36 + l0g + 4];
      f32x4 Ca, Cb;
      if (FULL) {
        Ca = *(const f32x4*)&CS[p][s * 36 + l0g];
        Cb = *(const f32x4*)&CS[p][s * 36 + l0g + 4];
      }
      float p8[8];
#pragma unroll
      for (int j = 0; j < 8; j++) {
        float dtj = (j < 4) ? dta[j] : dtb[j - 4];
        float dxj = (j < 4) ? xa[j]  : xb[j - 4];
        float Bj  = (j < 4) ? Ba[j]  : Bb[j - 4];
        float a = __builtin_amdgcn_exp2f(dtj * a2);
        h = a * h + dxj * Bj;
        if (FULL) {
          float Cj = (j < 4) ? Ca[j] : Cb[j - 4];
          p8[j] = h * Cj;
        }
      }
      if (FULL) {
#pragma unroll
        for (int half = 0; half < 2; half++) {
          float q0 = quad_sum(p8[half * 4 + 0]);
          float q1 = quad_sum(p8[half * 4 + 1]);
          float q2 = quad_sum(p8[half * 4 + 2]);
          float q3 = quad_sum(p8[half * 4 + 3]);
          float v01 = sb0 ? q1 : q0;
          float v23 = sb0 ? q3 : q2;
          ywp[g * 8 + half * 4] = sb1 ? v23 : v01;
        }
      }
    }
    if (FULL) {
      // epilogue: lane (dl,s) covers channel d, l = c*32 + s*2 + {0,1}
      f32x2 y0 = *(const f32x2*)&ysh[(dl * 4 + 0) * 36 + s * 2];
      f32x2 y1 = *(const f32x2*)&ysh[(dl * 4 + 1) * 36 + s * 2];
      f32x2 y2 = *(const f32x2*)&ysh[(dl * 4 + 2) * 36 + s * 2];
      f32x2 y3 = *(const f32x2*)&ysh[(dl * 4 + 3) * 36 + s * 2];
      f32x2 ys = y0 + y1 + y2 + y3;
      unsigned int xcu = xcR[p][dl * 18 + s];
      unsigned int szu = szR[p][dl * 18 + s];
      float xcf[2] = {__uint_as_float(xcu << 16), __uint_as_float(xcu & 0xFFFF0000u)};
      float szf[2] = {__uint_as_float(szu << 16), __uint_as_float(szu & 0xFFFF0000u)};
      size_t rr0 = rbase + c * SCL + s * 2;
#pragma unroll
      for (int i = 0; i < 2; i++) {
        float yv = ys[i] + xcf[i] * dpv;
        ybf[(rr0 + i) * DINNER + d] = f2bf(yv * szf[i]);
      }
    }
    if (c < NSC - 1) {
      store32(p ^ 1, R);
      if (c < NSC - 2) load32(R, (c + 2) * SCL);
    }
  }
  if (!FULL) {
    sdt = row16_sum(sdt);                   // channel-total over the 16-lane row
    P[o] = __builtin_amdgcn_exp2f(a2 * sdt);
    HL[o] = h;
  }
}

__global__ void scan_comb(const float* __restrict__ P, const float* __restrict__ HL,
                          float* __restrict__ HIN) {
  int tg = blockIdx.x * 256 + threadIdx.x;  // 49152
  int s = tg & 15;
  int rem = tg >> 4;
  int d = rem % DINNER;
  int b = rem / DINNER;
  float h = 0.f;
  for (int g = 0; g < NSEG; g++) {
    size_t o = (((size_t)g * B_SZ + b) * DINNER + d) * 16 + s;
    HIN[o] = h;
    if (g < NSEG - 1) h = P[o] * h + HL[o];
  }
}

// -------------------------------------------------------------- launcher ----
extern "C" void kernel_launch(void* const* d_in, const int* in_sizes, int n_in,
                              void* d_out, int out_size, void* d_ws, size_t ws_size,
                              hipStream_t stream) {
  const float* x    = (const float*)d_in[0];
  const float* w1   = (const float*)d_in[1];
  const float* cw   = (const float*)d_in[2];
  const float* cb   = (const float*)d_in[3];
  const float* alog = (const float*)d_in[4];
  const float* Dp   = (const float*)d_in[5];
  const float* w2   = (const float*)d_in[6];
  const float* dtw  = (const float*)d_in[7];
  const float* dtb  = (const float*)d_in[8];
  const float* w3   = (const float*)d_in[9];
  float* out = (float*)d_out;
  char* ws = (char*)d_ws;

  size_t off = 0;
  auto alloc = [&](size_t bytes) { size_t o = off; off += (bytes + 255) & ~(size_t)255; return o; };
  // xz region reused: after conv + szT consume it, dtT and ybf overlay it.
  char*           xzr   = ws + alloc((size_t)M_ROWS * 3072 * 4);
  float*          xz    = (float*)xzr;
  float*          dtT   = (float*)xzr;                                          // [1536][4096] f32
  unsigned short* ybf   = (unsigned short*)(xzr + (size_t)DINNER * M_ROWS * 4); // [4096][1536] bf16
  float*          xdbl  = (float*)(ws + alloc((size_t)M_ROWS * 128 * 4));
  unsigned short* xbf   = (unsigned short*)(ws + alloc((size_t)M_ROWS * DMODEL * 2));
  unsigned short* w1bf  = (unsigned short*)(ws + alloc((size_t)2 * DINNER * DMODEL * 2));
  unsigned short* w2bf  = (unsigned short*)(ws + alloc((size_t)128 * DINNER * 2));
  unsigned short* w3bf  = (unsigned short*)(ws + alloc((size_t)DMODEL * DINNER * 2));
  unsigned short* dtlbf = (unsigned short*)(ws + alloc((size_t)M_ROWS * 64 * 2));
  unsigned short* dtwbf = (unsigned short*)(ws + alloc((size_t)DINNER * 64 * 2));
  unsigned short* xcbf  = (unsigned short*)(ws + alloc((size_t)M_ROWS * DINNER * 2));
  unsigned short* xcT   = (unsigned short*)(ws + alloc((size_t)DINNER * M_ROWS * 2));
  unsigned short* szbf  = (unsigned short*)(ws + alloc((size_t)DINNER * M_ROWS * 2));
  float*          BCt   = (float*)(ws + alloc((size_t)B_SZ * 32 * L_SEQ * 4));
  float*          Pbuf  = (float*)(ws + alloc((size_t)NSEG * B_SZ * DINNER * 16 * 4));
  float*          HLbuf = (float*)(ws + alloc((size_t)NSEG * B_SZ * DINNER * 16 * 4));
  float*          HINb  = (float*)(ws + alloc((size_t)NSEG * B_SZ * DINNER * 16 * 4));

  // 1. casts
  cast_all_kernel<<<27264, 256, 0, stream>>>(x, w1, w2, w3, dtw, xbf, w1bf, w2bf, w3bf, dtwbf);
  // 2. xz = x @ W_in^T
  gemm_bt<0><<<dim3(32, 24), 256, 0, stream>>>(xbf, w1bf, xz, DMODEL, DMODEL, 3072, nullptr);
  // 3. conv+SiLU -> xcbf (row) + xcT (transposed), fused
  conv_silu_t<<<dim3(64, 24), 256, 0, stream>>>(xz, cw, cb, xcbf, xcT);
  // 4. szT = silu(z)^T
  transpose_silu<<<dim3(64, 24), 256, 0, stream>>>(xz, szbf);
  // 5. x_dbl = xc @ W_x^T, split-K x8 with atomic accumulate
  hipMemsetAsync(xdbl, 0, (size_t)M_ROWS * 128 * 4, stream);
  gemm_bt<3><<<dim3(32, 1, 8), 256, 0, stream>>>(xcbf, w2bf, xdbl, DINNER, DINNER / 8, 128, nullptr);
  // 6. dt_low cast + B/C transpose (merged)
  xdbl_pack_kernel<<<1152, 256, 0, stream>>>(xdbl, dtlbf, BCt);
  // 7. dtT = softplus(W_dt @ dt_low^T + b)  [1536][4096], overlays xz
  gemm_bt<2><<<dim3(12, 32), 256, 0, stream>>>(dtwbf, dtlbf, dtT, 64, 64, M_ROWS, dtb);
  // 8-10. segmented scan
  scan_seg<0><<<dim3(384, 2, NSEG - 1), 64, 0, stream>>>(dtT, xcT, BCt, szbf, alog, Dp,
                                                         nullptr, Pbuf, HLbuf, nullptr);
  scan_comb<<<192, 256, 0, stream>>>(Pbuf, HLbuf, HINb);
  scan_seg<1><<<dim3(384, 2, NSEG), 64, 0, stream>>>(dtT, xcT, BCt, szbf, alog, Dp,
                                                     HINb, nullptr, nullptr, ybf);
  // 11. out = y @ W_out^T
  gemm_bt<0><<<dim3(32, 6), 256, 0, stream>>>(ybf, w3bf, out, DINNER, DINNER, 768, nullptr);
}

// Round 7
// 314.608 us; speedup vs baseline: 1.2934x; 1.0569x over previous
//
#include <hip/hip_runtime.h>
#include <stdint.h>

#define B_SZ    2
#define L_SEQ   2048
#define DMODEL  768
#define DSTATE  16
#define DINNER  1536
#define DTRANK  48
#define M_ROWS  4096      // B*L
#define NSEG    4
#define SEGL    512
#define NSC     16        // superchunks per segment
#define SCL     32        // steps per superchunk
#define KSPLIT  8         // gemm2 split-K slabs

typedef __attribute__((ext_vector_type(8))) short bf16x8;
typedef __attribute__((ext_vector_type(4))) float f32x4;
typedef __attribute__((ext_vector_type(2))) float f32x2;
typedef __attribute__((ext_vector_type(4))) unsigned int u32x4;
typedef __attribute__((ext_vector_type(2))) unsigned int u32x2;

__device__ __forceinline__ unsigned short f2bf(float f) {
  unsigned int u = __float_as_uint(f);
  u += 0x7FFFu + ((u >> 16) & 1u);          // RNE
  return (unsigned short)(u >> 16);
}
__device__ __forceinline__ unsigned int pack2bf(float a, float b) {
  return (unsigned int)f2bf(a) | ((unsigned int)f2bf(b) << 16);
}
__device__ __forceinline__ float bf2f(unsigned short h) {
  return __uint_as_float(((unsigned int)h) << 16);
}
__device__ __forceinline__ float fexp(float x) {
  return __builtin_amdgcn_exp2f(x * 1.44269504088896340736f);
}
__device__ __forceinline__ float sigm(float x) {
  return 1.0f / (1.0f + fexp(-x));
}

template <int CTRL>
__device__ __forceinline__ float dpp_add(float v) {
  int x = __builtin_amdgcn_update_dpp(0, __float_as_int(v), CTRL, 0xF, 0xF, true);
  return v + __int_as_float(x);
}
__device__ __forceinline__ float quad_sum(float v) {
  v = dpp_add<0xB1>(v);   // quad_perm [1,0,3,2]
  v = dpp_add<0x4E>(v);   // quad_perm [2,3,0,1]
  return v;
}
__device__ __forceinline__ float row16_sum(float v) {
  v = dpp_add<0xB1>(v);
  v = dpp_add<0x4E>(v);
  v = dpp_add<0x124>(v);  // row_ror:4
  v = dpp_add<0x128>(v);  // row_ror:8
  return v;
}

// ---------------------------------------------------------------- casts ----
__global__ void cast_all_kernel(const float* __restrict__ x, const float* __restrict__ w1,
                                const float* __restrict__ w2, const float* __restrict__ w3,
                                const float* __restrict__ dtw,
                                unsigned short* __restrict__ xbf, unsigned short* __restrict__ w1bf,
                                unsigned short* __restrict__ w2bf, unsigned short* __restrict__ w3bf,
                                unsigned short* __restrict__ dtwbf) {
  int i = blockIdx.x * 256 + threadIdx.x;
  const int n_x = M_ROWS * DMODEL;
  const int n_w1 = 2 * DINNER * DMODEL;
  const int n_w3 = DMODEL * DINNER;
  const int n_w2 = 128 * DINNER;
  const int n_dtw = DINNER * 64;
  if (i < n_x)  { xbf[i] = f2bf(x[i]); return; }  i -= n_x;
  if (i < n_w1) { w1bf[i] = f2bf(w1[i]); return; } i -= n_w1;
  if (i < n_w3) { w3bf[i] = f2bf(w3[i]); return; } i -= n_w3;
  if (i < n_w2) {
    int row = i / DINNER, col = i - row * DINNER;
    w2bf[i] = (row < (DTRANK + 2 * DSTATE)) ? f2bf(w2[row * DINNER + col]) : (unsigned short)0;
    return;
  }
  i -= n_w2;
  if (i < n_dtw) {
    int row = i >> 6, col = i & 63;
    dtwbf[i] = (col < DTRANK) ? f2bf(dtw[row * DTRANK + col]) : (unsigned short)0;
  }
}

// merged: reduce 8 gemm2 slabs + cast dt_low (padded K=64) + B/C transpose
__global__ void xdbl_pack_kernel(const float* __restrict__ xdblS,
                                 unsigned short* __restrict__ dtlbf,
                                 float* __restrict__ BCt) {
  const int SLAB = M_ROWS * 128;
  int i = blockIdx.x * 256 + threadIdx.x;
  const int n_dtl = M_ROWS * 64;            // 262144
  if (i < n_dtl) {
    int row = i >> 6, col = i & 63;
    if (col < DTRANK) {
      float v = 0.f;
#pragma unroll
      for (int z = 0; z < KSPLIT; z++) v += xdblS[(size_t)z * SLAB + row * 128 + col];
      dtlbf[i] = f2bf(v);
    } else dtlbf[i] = 0;
    return;
  }
  i -= n_dtl;                               // 32768 entries
  int l4 = i & 511;
  int j  = (i >> 9) & 31;
  int b  = (i >> 14) & 1;
  f32x4 o;
#pragma unroll
  for (int k = 0; k < 4; k++) {
    float v = 0.f;
    size_t base = ((size_t)b * L_SEQ + l4 * 4 + k) * 128 + DTRANK + j;
#pragma unroll
    for (int z = 0; z < KSPLIT; z++) v += xdblS[(size_t)z * SLAB + base];
    o[k] = v;
  }
  *(f32x4*)(BCt + ((size_t)b * 32 + j) * L_SEQ + l4 * 4) = o;
}

// --------------------------------------------------- bf16 MFMA GEMM (B^T) ----
// C[z*slab + m*ldc + n] = sum_{k in [bz*KS, bz*KS+KS)} A[m][k]*Bt[n][k].
// EPI: 0 plain store; 2 softplus(acc+bias[row]).
template <int EPI>
__global__ __launch_bounds__(256, 2) void gemm_bt(
    const unsigned short* __restrict__ A, const unsigned short* __restrict__ Bt,
    float* __restrict__ C, int K, int KS, int ldc, long slab,
    const float* __restrict__ bias) {
  __shared__ unsigned short As[128 * 40];
  __shared__ unsigned short Bs[128 * 40];
  const int tid = threadIdx.x;
  const int m0 = blockIdx.x * 128;
  const int n0 = blockIdx.y * 128;
  const int ks = blockIdx.z * KS, ke = ks + KS;
  float* Cz = C + (size_t)blockIdx.z * slab;
  const int lane = tid & 63;
  const int wave = tid >> 6;
  const int wr = (wave >> 1) * 64, wc = (wave & 1) * 64;
  const int lm = lane & 15, q = lane >> 4;
  const int r = tid >> 2, sg = (tid & 3) * 8;

  f32x4 acc[4][4] = {};

  for (int k0 = ks; k0 < ke; k0 += 32) {
    u32x4 a0 = *(const u32x4*)(A + (size_t)(m0 + r) * K + k0 + sg);
    u32x4 a1 = *(const u32x4*)(A + (size_t)(m0 + r + 64) * K + k0 + sg);
    u32x4 b0 = *(const u32x4*)(Bt + (size_t)(n0 + r) * K + k0 + sg);
    u32x4 b1 = *(const u32x4*)(Bt + (size_t)(n0 + r + 64) * K + k0 + sg);
    __syncthreads();
    *(u32x4*)&As[r * 40 + sg] = a0;
    *(u32x4*)&As[(r + 64) * 40 + sg] = a1;
    *(u32x4*)&Bs[r * 40 + sg] = b0;
    *(u32x4*)&Bs[(r + 64) * 40 + sg] = b1;
    __syncthreads();
    bf16x8 af[4], bq[4];
#pragma unroll
    for (int mt = 0; mt < 4; mt++)
      af[mt] = *(const bf16x8*)&As[(wr + mt * 16 + lm) * 40 + q * 8];
#pragma unroll
    for (int nt = 0; nt < 4; nt++)
      bq[nt] = *(const bf16x8*)&Bs[(wc + nt * 16 + lm) * 40 + q * 8];
#pragma unroll
    for (int mt = 0; mt < 4; mt++)
#pragma unroll
      for (int nt = 0; nt < 4; nt++)
        acc[mt][nt] = __builtin_amdgcn_mfma_f32_16x16x32_bf16(af[mt], bq[nt], acc[mt][nt], 0, 0, 0);
  }

#pragma unroll
  for (int mt = 0; mt < 4; mt++) {
    int row0 = m0 + wr + mt * 16 + q * 4;
    float bs4[4];
    if (EPI == 2) {
#pragma unroll
      for (int i = 0; i < 4; i++) bs4[i] = bias[row0 + i];
    }
#pragma unroll
    for (int nt = 0; nt < 4; nt++) {
      int col = n0 + wc + nt * 16 + lm;
#pragma unroll
      for (int i = 0; i < 4; i++) {
        float v = acc[mt][nt][i];
        if (EPI == 2) {
          v += bs4[i];
          v = (v > 15.f) ? v : log1pf(fexp(v));
        }
        Cz[(size_t)(row0 + i) * ldc + col] = v;
      }
    }
  }
}

// ------------------- fused depthwise conv + SiLU -> xcbf (row) + xcT (col) ----
__global__ __launch_bounds__(256) void conv_silu_t(const float* __restrict__ xz,
                                                   const float* __restrict__ cw,
                                                   const float* __restrict__ cb,
                                                   unsigned short* __restrict__ xcbf,
                                                   unsigned short* __restrict__ xcT) {
  __shared__ float tl[67 * 68];
  __shared__ unsigned short xs[64 * 80];
  __shared__ float cws[64 * 4];
  __shared__ float cbs[64];
  const int r0 = blockIdx.x * 64;     // global row b*L+l
  const int c0 = blockIdx.y * 64;     // channel d
  const int t = threadIdx.x;
  cws[t] = cw[(c0 + (t >> 2)) * 4 + (t & 3)];
  if (t < 64) cbs[t] = cb[c0 + t];
  const bool lowedge = (r0 & (L_SEQ - 1)) == 0;
#pragma unroll
  for (int it = 0; it < 5; it++) {
    int idx = t + it * 256;
    int rr = idx >> 4;
    int cs4 = (idx & 15) * 4;
    if (rr < 67) {
      f32x4 v;
      if (lowedge && rr < 3) v = (f32x4){0.f, 0.f, 0.f, 0.f};
      else v = *(const f32x4*)(xz + (size_t)(r0 + rr - 3) * 3072 + c0 + cs4);
      *(f32x4*)&tl[rr * 68 + cs4] = v;
    }
  }
  __syncthreads();
  const int cs = (t & 15) * 4;
  f32x4 w0, w1, w2, w3, cbv;
#pragma unroll
  for (int j = 0; j < 4; j++) {
    w0[j] = cws[(cs + j) * 4 + 0];
    w1[j] = cws[(cs + j) * 4 + 1];
    w2[j] = cws[(cs + j) * 4 + 2];
    w3[j] = cws[(cs + j) * 4 + 3];
    cbv[j] = cbs[cs + j];
  }
#pragma unroll
  for (int it = 0; it < 4; it++) {
    int r = (t >> 4) + it * 16;
    f32x4 t0 = *(const f32x4*)&tl[(r + 0) * 68 + cs];
    f32x4 t1 = *(const f32x4*)&tl[(r + 1) * 68 + cs];
    f32x4 t2 = *(const f32x4*)&tl[(r + 2) * 68 + cs];
    f32x4 t3 = *(const f32x4*)&tl[(r + 3) * 68 + cs];
    f32x4 acc = cbv + w0 * t0 + w1 * t1 + w2 * t2 + w3 * t3;
#pragma unroll
    for (int j = 0; j < 4; j++) acc[j] = acc[j] * sigm(acc[j]);
    u32x2 pk;
    pk[0] = pack2bf(acc[0], acc[1]);
    pk[1] = pack2bf(acc[2], acc[3]);
    *(u32x2*)(xcbf + (size_t)(r0 + r) * DINNER + c0 + cs) = pk;
    *(u32x2*)&xs[r * 80 + cs] = pk;
  }
  __syncthreads();
#pragma unroll
  for (int it = 0; it < 2; it++) {
    int idx = t + it * 256;
    int cc = idx & 63, rs = idx >> 6;
    unsigned int w[4];
#pragma unroll
    for (int p = 0; p < 4; p++) {
      unsigned int lo = xs[(rs * 8 + 2 * p) * 80 + cc];
      unsigned int hi = xs[(rs * 8 + 2 * p + 1) * 80 + cc];
      w[p] = lo | (hi << 16);
    }
    *(u32x4*)(xcT + (size_t)(c0 + cc) * M_ROWS + r0 + rs * 8) = *(u32x4*)w;
  }
}

// --------------------------------------- z-half silu + transpose -> szT ----
__global__ __launch_bounds__(256) void transpose_silu(const float* __restrict__ xz,
                                                      unsigned short* __restrict__ out) {
  __shared__ float tl[64 * 68];
  const int r0 = blockIdx.x * 64;
  const int c0 = blockIdx.y * 64;
  const int tid = threadIdx.x;
#pragma unroll
  for (int it = 0; it < 4; it++) {
    int idx = tid + it * 256;
    int rr = idx >> 4, cs = idx & 15;
    f32x4 v = *(const f32x4*)(xz + (size_t)(r0 + rr) * 3072 + DINNER + c0 + cs * 4);
#pragma unroll
    for (int p = 0; p < 4; p++) v[p] = v[p] * sigm(v[p]);
    *(f32x4*)&tl[rr * 68 + cs * 4] = v;
  }
  __syncthreads();
#pragma unroll
  for (int it = 0; it < 2; it++) {
    int idx = tid + it * 256;
    int cc = idx & 63, rs = idx >> 6;
    unsigned int w[4];
#pragma unroll
    for (int p = 0; p < 4; p++)
      w[p] = pack2bf(tl[(rs * 8 + 2 * p) * 68 + cc], tl[(rs * 8 + 2 * p + 1) * 68 + cc]);
    *(u32x4*)(out + (size_t)(c0 + cc) * M_ROWS + r0 + rs * 8) = *(u32x4*)w;
  }
}

// ------------------------------------------------ segmented selective scan ----
// One wave per (4-channel group, batch, 512-step segment). LDS double-buffered
// 32-step superchunks (coalesced global->reg->LDS, consume from LDS).
struct SC32 { f32x2 dt; unsigned int xc, sz; f32x4 B0, B1, C0, C1; };

template <int FULL>
__global__ __launch_bounds__(64) void scan_seg(
    const float* __restrict__ dtT, const unsigned short* __restrict__ xcT,
    const float* __restrict__ BCt, const unsigned short* __restrict__ szT,
    const float* __restrict__ A_log, const float* __restrict__ Dp,
    const float* __restrict__ HIN, float* __restrict__ P, float* __restrict__ HL,
    unsigned short* __restrict__ ybf) {
  __shared__ float dtS[2][4 * 36];
  __shared__ float dtxS[2][4 * 36];
  __shared__ float BS[2][16 * 36];
  __shared__ float CS[2][16 * 36];
  __shared__ unsigned int xcR[2][4 * 18];
  __shared__ unsigned int szR[2][4 * 18];
  __shared__ float ysh[16 * 36];
  const int lane = threadIdx.x;
  const int s = lane & 15, dl = lane >> 4;
  const int d0 = blockIdx.x * 4;
  const int d = d0 + dl;
  const int b = blockIdx.y;
  const int seg = blockIdx.z;
  const int lseg = seg * SEGL;
  const size_t rbase = (size_t)b * L_SEQ + lseg;
  const float a2 = -fexp(A_log[d * 16 + s]) * 1.44269504f;
  const float dpv = Dp[d];
  const float* dtbase = dtT + (size_t)d0 * M_ROWS + rbase;
  const unsigned short* xcbase = xcT + (size_t)d0 * M_ROWS + rbase;
  const unsigned short* szbase = szT + (size_t)d0 * M_ROWS + rbase;
  const float* Bbase = BCt + (size_t)b * 32 * L_SEQ + lseg;
  const float* Cbase = Bbase + 16 * L_SEQ;
  const int ch = lane >> 4, li = lane & 15;     // dt/xc/sz staging map
  const int s4 = lane >> 2, lj = lane & 3;      // B/C staging map
  float* ywp = &ysh[(dl * 4 + (s >> 2)) * 36 + (s & 3)];
  const bool sb0 = (s & 1) != 0, sb1 = (s & 2) != 0;
  float h = 0.f, sdt = 0.f;
  size_t o = (((size_t)seg * B_SZ + b) * DINNER + d) * 16 + s;
  if (FULL) h = HIN[o];

  auto load32 = [&](SC32& R, int l0) {
    R.dt = *(const f32x2*)(dtbase + (size_t)ch * M_ROWS + l0 + li * 2);
    R.xc = *(const unsigned int*)(xcbase + (size_t)ch * M_ROWS + l0 + li * 2);
    if (FULL) R.sz = *(const unsigned int*)(szbase + (size_t)ch * M_ROWS + l0 + li * 2);
    R.B0 = *(const f32x4*)(Bbase + (size_t)s4 * L_SEQ + l0 + lj * 8);
    R.B1 = *(const f32x4*)(Bbase + (size_t)s4 * L_SEQ + l0 + lj * 8 + 4);
    if (FULL) {
      R.C0 = *(const f32x4*)(Cbase + (size_t)s4 * L_SEQ + l0 + lj * 8);
      R.C1 = *(const f32x4*)(Cbase + (size_t)s4 * L_SEQ + l0 + lj * 8 + 4);
    }
  };
  auto store32 = [&](int p, const SC32& R) {
    if (!FULL) sdt += R.dt[0] + R.dt[1];
    f32x2 xf, dtx;
    xf[0] = __uint_as_float(R.xc << 16);
    xf[1] = __uint_as_float(R.xc & 0xFFFF0000u);
    dtx = R.dt * xf;
    *(f32x2*)&dtS[p][ch * 36 + li * 2] = R.dt;
    *(f32x2*)&dtxS[p][ch * 36 + li * 2] = dtx;
    if (FULL) {
      xcR[p][ch * 18 + li] = R.xc;
      szR[p][ch * 18 + li] = R.sz;
    }
    *(f32x4*)&BS[p][s4 * 36 + lj * 8] = R.B0;
    *(f32x4*)&BS[p][s4 * 36 + lj * 8 + 4] = R.B1;
    if (FULL) {
      *(f32x4*)&CS[p][s4 * 36 + lj * 8] = R.C0;
      *(f32x4*)&CS[p][s4 * 36 + lj * 8 + 4] = R.C1;
    }
  };

  SC32 R;
  load32(R, 0);
  store32(0, R);
  load32(R, SCL);

#pragma unroll 1
  for (int c = 0; c < NSC; c++) {
    const int p = c & 1;
#pragma unroll
    for (int g = 0; g < 4; g++) {
      const int l0g = g * 8;
      f32x4 dta = *(const f32x4*)&dtS[p][dl * 36 + l0g];
      f32x4 dtb = *(const f32x4*)&dtS[p][dl * 36 + l0g + 4];
      f32x4 xa  = *(const f32x4*)&dtxS[p][dl * 36 + l0g];
      f32x4 xb  = *(const f32x4*)&dtxS[p][dl * 36 + l0g + 4];
      f32x4 Ba  = *(const f32x4*)&BS[p][s * 36 + l0g];
      f32x4 Bb  = *(const f32x4*)&BS[p][s * 36 + l0g + 4];
      f32x4 Ca, Cb;
      if (FULL) {
        Ca = *(const f32x4*)&CS[p][s * 36 + l0g];
        Cb = *(const f32x4*)&CS[p][s * 36 + l0g + 4];
      }
      float p8[8];
#pragma unroll
      for (int j = 0; j < 8; j++) {
        float dtj = (j < 4) ? dta[j] : dtb[j - 4];
        float dxj = (j < 4) ? xa[j]  : xb[j - 4];
        float Bj  = (j < 4) ? Ba[j]  : Bb[j - 4];
        float a = __builtin_amdgcn_exp2f(dtj * a2);
        h = a * h + dxj * Bj;
        if (FULL) {
          float Cj = (j < 4) ? Ca[j] : Cb[j - 4];
          p8[j] = h * Cj;
        }
      }
      if (FULL) {
#pragma unroll
        for (int half = 0; half < 2; half++) {
          float q0 = quad_sum(p8[half * 4 + 0]);
          float q1 = quad_sum(p8[half * 4 + 1]);
          float q2 = quad_sum(p8[half * 4 + 2]);
          float q3 = quad_sum(p8[half * 4 + 3]);
          float v01 = sb0 ? q1 : q0;
          float v23 = sb0 ? q3 : q2;
          ywp[g * 8 + half * 4] = sb1 ? v23 : v01;
        }
      }
    }
    if (FULL) {
      f32x2 y0 = *(const f32x2*)&ysh[(dl * 4 + 0) * 36 + s * 2];
      f32x2 y1 = *(const f32x2*)&ysh[(dl * 4 + 1) * 36 + s * 2];
      f32x2 y2 = *(const f32x2*)&ysh[(dl * 4 + 2) * 36 + s * 2];
      f32x2 y3 = *(const f32x2*)&ysh[(dl * 4 + 3) * 36 + s * 2];
      f32x2 ys = y0 + y1 + y2 + y3;
      unsigned int xcu = xcR[p][dl * 18 + s];
      unsigned int szu = szR[p][dl * 18 + s];
      float xcf[2] = {__uint_as_float(xcu << 16), __uint_as_float(xcu & 0xFFFF0000u)};
      float szf[2] = {__uint_as_float(szu << 16), __uint_as_float(szu & 0xFFFF0000u)};
      size_t rr0 = rbase + c * SCL + s * 2;
#pragma unroll
      for (int i = 0; i < 2; i++) {
        float yv = ys[i] + xcf[i] * dpv;
        ybf[(rr0 + i) * DINNER + d] = f2bf(yv * szf[i]);
      }
    }
    if (c < NSC - 1) {
      store32(p ^ 1, R);
      if (c < NSC - 2) load32(R, (c + 2) * SCL);
    }
  }
  if (!FULL) {
    sdt = row16_sum(sdt);
    P[o] = __builtin_amdgcn_exp2f(a2 * sdt);
    HL[o] = h;
  }
}

__global__ void scan_comb(const float* __restrict__ P, const float* __restrict__ HL,
                          float* __restrict__ HIN) {
  int tg = blockIdx.x * 256 + threadIdx.x;  // 49152
  int s = tg & 15;
  int rem = tg >> 4;
  int d = rem % DINNER;
  int b = rem / DINNER;
  float h = 0.f;
  for (int g = 0; g < NSEG; g++) {
    size_t o = (((size_t)g * B_SZ + b) * DINNER + d) * 16 + s;
    HIN[o] = h;
    if (g < NSEG - 1) h = P[o] * h + HL[o];
  }
}

// -------------------------------------------------------------- launcher ----
extern "C" void kernel_launch(void* const* d_in, const int* in_sizes, int n_in,
                              void* d_out, int out_size, void* d_ws, size_t ws_size,
                              hipStream_t stream) {
  const float* x    = (const float*)d_in[0];
  const float* w1   = (const float*)d_in[1];
  const float* cw   = (const float*)d_in[2];
  const float* cb   = (const float*)d_in[3];
  const float* alog = (const float*)d_in[4];
  const float* Dp   = (const float*)d_in[5];
  const float* w2   = (const float*)d_in[6];
  const float* dtw  = (const float*)d_in[7];
  const float* dtb  = (const float*)d_in[8];
  const float* w3   = (const float*)d_in[9];
  float* out = (float*)d_out;
  char* ws = (char*)d_ws;

  size_t off = 0;
  auto alloc = [&](size_t bytes) { size_t o = off; off += (bytes + 255) & ~(size_t)255; return o; };
  // xz region reused: after conv + szT consume it, dtT and ybf overlay it.
  char*           xzr   = ws + alloc((size_t)M_ROWS * 3072 * 4);
  float*          xz    = (float*)xzr;
  float*          dtT   = (float*)xzr;                                          // [1536][4096] f32
  unsigned short* ybf   = (unsigned short*)(xzr + (size_t)DINNER * M_ROWS * 4); // [4096][1536] bf16
  float*          xdblS = (float*)(ws + alloc((size_t)KSPLIT * M_ROWS * 128 * 4)); // 8 slabs, 16.8 MB
  unsigned short* xbf   = (unsigned short*)(ws + alloc((size_t)M_ROWS * DMODEL * 2));
  unsigned short* w1bf  = (unsigned short*)(ws + alloc((size_t)2 * DINNER * DMODEL * 2));
  unsigned short* w2bf  = (unsigned short*)(ws + alloc((size_t)128 * DINNER * 2));
  unsigned short* w3bf  = (unsigned short*)(ws + alloc((size_t)DMODEL * DINNER * 2));
  unsigned short* dtlbf = (unsigned short*)(ws + alloc((size_t)M_ROWS * 64 * 2));
  unsigned short* dtwbf = (unsigned short*)(ws + alloc((size_t)DINNER * 64 * 2));
  unsigned short* xcbf  = (unsigned short*)(ws + alloc((size_t)M_ROWS * DINNER * 2));
  unsigned short* xcT   = (unsigned short*)(ws + alloc((size_t)DINNER * M_ROWS * 2));
  unsigned short* szbf  = (unsigned short*)(ws + alloc((size_t)DINNER * M_ROWS * 2));
  float*          BCt   = (float*)(ws + alloc((size_t)B_SZ * 32 * L_SEQ * 4));
  float*          Pbuf  = (float*)(ws + alloc((size_t)NSEG * B_SZ * DINNER * 16 * 4));
  float*          HLbuf = (float*)(ws + alloc((size_t)NSEG * B_SZ * DINNER * 16 * 4));
  float*          HINb  = (float*)(ws + alloc((size_t)NSEG * B_SZ * DINNER * 16 * 4));

  // 1. casts
  cast_all_kernel<<<27264, 256, 0, stream>>>(x, w1, w2, w3, dtw, xbf, w1bf, w2bf, w3bf, dtwbf);
  // 2. xz = x @ W_in^T
  gemm_bt<0><<<dim3(32, 24), 256, 0, stream>>>(xbf, w1bf, xz, DMODEL, DMODEL, 3072, 0, nullptr);
  // 3. conv+SiLU -> xcbf (row) + xcT (transposed), fused
  conv_silu_t<<<dim3(64, 24), 256, 0, stream>>>(xz, cw, cb, xcbf, xcT);
  // 4. szT = silu(z)^T
  transpose_silu<<<dim3(64, 24), 256, 0, stream>>>(xz, szbf);
  // 5. x_dbl slabs = xc @ W_x^T, split-K x8 with PRIVATE slabs (no atomics)
  gemm_bt<0><<<dim3(32, 1, KSPLIT), 256, 0, stream>>>(xcbf, w2bf, xdblS, DINNER,
                                                      DINNER / KSPLIT, 128,
                                                      (long)M_ROWS * 128, nullptr);
  // 6. slab-reduce + dt_low cast + B/C transpose (merged)
  xdbl_pack_kernel<<<1152, 256, 0, stream>>>(xdblS, dtlbf, BCt);
  // 7. dtT = softplus(W_dt @ dt_low^T + b)  [1536][4096], overlays xz
  gemm_bt<2><<<dim3(12, 32), 256, 0, stream>>>(dtwbf, dtlbf, dtT, 64, 64, M_ROWS, 0, dtb);
  // 8-10. segmented scan
  scan_seg<0><<<dim3(384, 2, NSEG - 1), 64, 0, stream>>>(dtT, xcT, BCt, szbf, alog, Dp,
                                                         nullptr, Pbuf, HLbuf, nullptr);
  scan_comb<<<192, 256, 0, stream>>>(Pbuf, HLbuf, HINb);
  scan_seg<1><<<dim3(384, 2, NSEG), 64, 0, stream>>>(dtT, xcT, BCt, szbf, alog, Dp,
                                                     HINb, nullptr, nullptr, ybf);
  // 11. out = y @ W_out^T
  gemm_bt<0><<<dim3(32, 6), 256, 0, stream>>>(ybf, w3bf, out, DINNER, DINNER, 768, 0, nullptr);
}

// Round 8
// 304.595 us; speedup vs baseline: 1.3359x; 1.0329x over previous
//
#include <hip/hip_runtime.h>
#include <stdint.h>

#define B_SZ    2
#define L_SEQ   2048
#define DMODEL  768
#define DSTATE  16
#define DINNER  1536
#define DTRANK  48
#define M_ROWS  4096      // B*L
#define NSEG    8
#define SEGL    256
#define NSC     8         // superchunks per segment
#define SCL     32        // steps per superchunk
#define KSPLIT  8         // gemm2 split-K slabs

typedef __attribute__((ext_vector_type(8))) short bf16x8;
typedef __attribute__((ext_vector_type(4))) float f32x4;
typedef __attribute__((ext_vector_type(2))) float f32x2;
typedef __attribute__((ext_vector_type(4))) unsigned int u32x4;
typedef __attribute__((ext_vector_type(2))) unsigned int u32x2;

__device__ __forceinline__ unsigned short f2bf(float f) {
  unsigned int u = __float_as_uint(f);
  u += 0x7FFFu + ((u >> 16) & 1u);          // RNE
  return (unsigned short)(u >> 16);
}
__device__ __forceinline__ unsigned int pack2bf(float a, float b) {
  return (unsigned int)f2bf(a) | ((unsigned int)f2bf(b) << 16);
}
__device__ __forceinline__ float bf2f(unsigned short h) {
  return __uint_as_float(((unsigned int)h) << 16);
}
__device__ __forceinline__ float fexp(float x) {
  return __builtin_amdgcn_exp2f(x * 1.44269504088896340736f);
}
__device__ __forceinline__ float sigm(float x) {
  return 1.0f / (1.0f + fexp(-x));
}

template <int CTRL>
__device__ __forceinline__ float dpp_add(float v) {
  int x = __builtin_amdgcn_update_dpp(0, __float_as_int(v), CTRL, 0xF, 0xF, true);
  return v + __int_as_float(x);
}
__device__ __forceinline__ float quad_sum(float v) {
  v = dpp_add<0xB1>(v);   // quad_perm [1,0,3,2]
  v = dpp_add<0x4E>(v);   // quad_perm [2,3,0,1]
  return v;
}
__device__ __forceinline__ float row16_sum(float v) {
  v = dpp_add<0xB1>(v);
  v = dpp_add<0x4E>(v);
  v = dpp_add<0x124>(v);  // row_ror:4
  v = dpp_add<0x128>(v);  // row_ror:8
  return v;
}

// ---------------------------------------------------------------- casts ----
__global__ void cast_all_kernel(const float* __restrict__ x, const float* __restrict__ w1,
                                const float* __restrict__ w2, const float* __restrict__ w3,
                                const float* __restrict__ dtw,
                                unsigned short* __restrict__ xbf, unsigned short* __restrict__ w1bf,
                                unsigned short* __restrict__ w2bf, unsigned short* __restrict__ w3bf,
                                unsigned short* __restrict__ dtwbf) {
  int i = blockIdx.x * 256 + threadIdx.x;
  const int n_x = M_ROWS * DMODEL;
  const int n_w1 = 2 * DINNER * DMODEL;
  const int n_w3 = DMODEL * DINNER;
  const int n_w2 = 128 * DINNER;
  const int n_dtw = DINNER * 64;
  if (i < n_x)  { xbf[i] = f2bf(x[i]); return; }  i -= n_x;
  if (i < n_w1) { w1bf[i] = f2bf(w1[i]); return; } i -= n_w1;
  if (i < n_w3) { w3bf[i] = f2bf(w3[i]); return; } i -= n_w3;
  if (i < n_w2) {
    int row = i / DINNER, col = i - row * DINNER;
    w2bf[i] = (row < (DTRANK + 2 * DSTATE)) ? f2bf(w2[row * DINNER + col]) : (unsigned short)0;
    return;
  }
  i -= n_w2;
  if (i < n_dtw) {
    int row = i >> 6, col = i & 63;
    dtwbf[i] = (col < DTRANK) ? f2bf(dtw[row * DTRANK + col]) : (unsigned short)0;
  }
}

// merged: reduce 8 gemm2 slabs + cast dt_low (padded K=64) + B/C transpose
__global__ void xdbl_pack_kernel(const float* __restrict__ xdblS,
                                 unsigned short* __restrict__ dtlbf,
                                 float* __restrict__ BCt) {
  const int SLAB = M_ROWS * 128;
  int i = blockIdx.x * 256 + threadIdx.x;
  const int n_dtl = M_ROWS * 64;            // 262144
  if (i < n_dtl) {
    int row = i >> 6, col = i & 63;
    if (col < DTRANK) {
      float v = 0.f;
#pragma unroll
      for (int z = 0; z < KSPLIT; z++) v += xdblS[(size_t)z * SLAB + row * 128 + col];
      dtlbf[i] = f2bf(v);
    } else dtlbf[i] = 0;
    return;
  }
  i -= n_dtl;                               // 32768 entries
  int l4 = i & 511;
  int j  = (i >> 9) & 31;
  int b  = (i >> 14) & 1;
  f32x4 o;
#pragma unroll
  for (int k = 0; k < 4; k++) {
    float v = 0.f;
    size_t base = ((size_t)b * L_SEQ + l4 * 4 + k) * 128 + DTRANK + j;
#pragma unroll
    for (int z = 0; z < KSPLIT; z++) v += xdblS[(size_t)z * SLAB + base];
    o[k] = v;
  }
  *(f32x4*)(BCt + ((size_t)b * 32 + j) * L_SEQ + l4 * 4) = o;
}

// --------------------------------------------------- bf16 MFMA GEMM (B^T) ----
// C[z*slab + m*ldc + n] = sum_{k in [bz*KS, bz*KS+KS)} A[m][k]*Bt[n][k].
// EPI: 0 plain store; 2 softplus(acc+bias[row]).
template <int EPI>
__global__ __launch_bounds__(256, 2) void gemm_bt(
    const unsigned short* __restrict__ A, const unsigned short* __restrict__ Bt,
    float* __restrict__ C, int K, int KS, int ldc, long slab,
    const float* __restrict__ bias) {
  __shared__ unsigned short As[128 * 40];
  __shared__ unsigned short Bs[128 * 40];
  const int tid = threadIdx.x;
  const int m0 = blockIdx.x * 128;
  const int n0 = blockIdx.y * 128;
  const int ks = blockIdx.z * KS, ke = ks + KS;
  float* Cz = C + (size_t)blockIdx.z * slab;
  const int lane = tid & 63;
  const int wave = tid >> 6;
  const int wr = (wave >> 1) * 64, wc = (wave & 1) * 64;
  const int lm = lane & 15, q = lane >> 4;
  const int r = tid >> 2, sg = (tid & 3) * 8;

  f32x4 acc[4][4] = {};

  for (int k0 = ks; k0 < ke; k0 += 32) {
    u32x4 a0 = *(const u32x4*)(A + (size_t)(m0 + r) * K + k0 + sg);
    u32x4 a1 = *(const u32x4*)(A + (size_t)(m0 + r + 64) * K + k0 + sg);
    u32x4 b0 = *(const u32x4*)(Bt + (size_t)(n0 + r) * K + k0 + sg);
    u32x4 b1 = *(const u32x4*)(Bt + (size_t)(n0 + r + 64) * K + k0 + sg);
    __syncthreads();
    *(u32x4*)&As[r * 40 + sg] = a0;
    *(u32x4*)&As[(r + 64) * 40 + sg] = a1;
    *(u32x4*)&Bs[r * 40 + sg] = b0;
    *(u32x4*)&Bs[(r + 64) * 40 + sg] = b1;
    __syncthreads();
    bf16x8 af[4], bq[4];
#pragma unroll
    for (int mt = 0; mt < 4; mt++)
      af[mt] = *(const bf16x8*)&As[(wr + mt * 16 + lm) * 40 + q * 8];
#pragma unroll
    for (int nt = 0; nt < 4; nt++)
      bq[nt] = *(const bf16x8*)&Bs[(wc + nt * 16 + lm) * 40 + q * 8];
#pragma unroll
    for (int mt = 0; mt < 4; mt++)
#pragma unroll
      for (int nt = 0; nt < 4; nt++)
        acc[mt][nt] = __builtin_amdgcn_mfma_f32_16x16x32_bf16(af[mt], bq[nt], acc[mt][nt], 0, 0, 0);
  }

#pragma unroll
  for (int mt = 0; mt < 4; mt++) {
    int row0 = m0 + wr + mt * 16 + q * 4;
    float bs4[4];
    if (EPI == 2) {
#pragma unroll
      for (int i = 0; i < 4; i++) bs4[i] = bias[row0 + i];
    }
#pragma unroll
    for (int nt = 0; nt < 4; nt++) {
      int col = n0 + wc + nt * 16 + lm;
#pragma unroll
      for (int i = 0; i < 4; i++) {
        float v = acc[mt][nt][i];
        if (EPI == 2) {
          v += bs4[i];
          v = (v > 15.f) ? v : log1pf(fexp(v));
        }
        Cz[(size_t)(row0 + i) * ldc + col] = v;
      }
    }
  }
}

// ------------------- fused depthwise conv + SiLU -> xcbf (row) + xcT (col) ----
__global__ __launch_bounds__(256) void conv_silu_t(const float* __restrict__ xz,
                                                   const float* __restrict__ cw,
                                                   const float* __restrict__ cb,
                                                   unsigned short* __restrict__ xcbf,
                                                   unsigned short* __restrict__ xcT) {
  __shared__ float tl[67 * 68];
  __shared__ unsigned short xs[64 * 80];
  __shared__ float cws[64 * 4];
  __shared__ float cbs[64];
  const int r0 = blockIdx.x * 64;     // global row b*L+l
  const int c0 = blockIdx.y * 64;     // channel d
  const int t = threadIdx.x;
  cws[t] = cw[(c0 + (t >> 2)) * 4 + (t & 3)];
  if (t < 64) cbs[t] = cb[c0 + t];
  const bool lowedge = (r0 & (L_SEQ - 1)) == 0;
#pragma unroll
  for (int it = 0; it < 5; it++) {
    int idx = t + it * 256;
    int rr = idx >> 4;
    int cs4 = (idx & 15) * 4;
    if (rr < 67) {
      f32x4 v;
      if (lowedge && rr < 3) v = (f32x4){0.f, 0.f, 0.f, 0.f};
      else v = *(const f32x4*)(xz + (size_t)(r0 + rr - 3) * 3072 + c0 + cs4);
      *(f32x4*)&tl[rr * 68 + cs4] = v;
    }
  }
  __syncthreads();
  const int cs = (t & 15) * 4;
  f32x4 w0, w1, w2, w3, cbv;
#pragma unroll
  for (int j = 0; j < 4; j++) {
    w0[j] = cws[(cs + j) * 4 + 0];
    w1[j] = cws[(cs + j) * 4 + 1];
    w2[j] = cws[(cs + j) * 4 + 2];
    w3[j] = cws[(cs + j) * 4 + 3];
    cbv[j] = cbs[cs + j];
  }
#pragma unroll
  for (int it = 0; it < 4; it++) {
    int r = (t >> 4) + it * 16;
    f32x4 t0 = *(const f32x4*)&tl[(r + 0) * 68 + cs];
    f32x4 t1 = *(const f32x4*)&tl[(r + 1) * 68 + cs];
    f32x4 t2 = *(const f32x4*)&tl[(r + 2) * 68 + cs];
    f32x4 t3 = *(const f32x4*)&tl[(r + 3) * 68 + cs];
    f32x4 acc = cbv + w0 * t0 + w1 * t1 + w2 * t2 + w3 * t3;
#pragma unroll
    for (int j = 0; j < 4; j++) acc[j] = acc[j] * sigm(acc[j]);
    u32x2 pk;
    pk[0] = pack2bf(acc[0], acc[1]);
    pk[1] = pack2bf(acc[2], acc[3]);
    *(u32x2*)(xcbf + (size_t)(r0 + r) * DINNER + c0 + cs) = pk;
    *(u32x2*)&xs[r * 80 + cs] = pk;
  }
  __syncthreads();
#pragma unroll
  for (int it = 0; it < 2; it++) {
    int idx = t + it * 256;
    int cc = idx & 63, rs = idx >> 6;
    unsigned int w[4];
#pragma unroll
    for (int p = 0; p < 4; p++) {
      unsigned int lo = xs[(rs * 8 + 2 * p) * 80 + cc];
      unsigned int hi = xs[(rs * 8 + 2 * p + 1) * 80 + cc];
      w[p] = lo | (hi << 16);
    }
    *(u32x4*)(xcT + (size_t)(c0 + cc) * M_ROWS + r0 + rs * 8) = *(u32x4*)w;
  }
}

// --------------------------------------- z-half silu + transpose -> szT ----
__global__ __launch_bounds__(256) void transpose_silu(const float* __restrict__ xz,
                                                      unsigned short* __restrict__ out) {
  __shared__ float tl[64 * 68];
  const int r0 = blockIdx.x * 64;
  const int c0 = blockIdx.y * 64;
  const int tid = threadIdx.x;
#pragma unroll
  for (int it = 0; it < 4; it++) {
    int idx = tid + it * 256;
    int rr = idx >> 4, cs = idx & 15;
    f32x4 v = *(const f32x4*)(xz + (size_t)(r0 + rr) * 3072 + DINNER + c0 + cs * 4);
#pragma unroll
    for (int p = 0; p < 4; p++) v[p] = v[p] * sigm(v[p]);
    *(f32x4*)&tl[rr * 68 + cs * 4] = v;
  }
  __syncthreads();
#pragma unroll
  for (int it = 0; it < 2; it++) {
    int idx = tid + it * 256;
    int cc = idx & 63, rs = idx >> 6;
    unsigned int w[4];
#pragma unroll
    for (int p = 0; p < 4; p++)
      w[p] = pack2bf(tl[(rs * 8 + 2 * p) * 68 + cc], tl[(rs * 8 + 2 * p + 1) * 68 + cc]);
    *(u32x4*)(out + (size_t)(c0 + cc) * M_ROWS + r0 + rs * 8) = *(u32x4*)w;
  }
}

// ------------------------------------------------ segmented selective scan ----
// One wave per (4-channel group, batch, 256-step segment). Single-buffer LDS,
// no intra-wave pipeline: occupancy (TLP) hides latency. Template-conditional
// LDS keeps FULL=0 at ~3.5 KB and FULL=1 at ~8.6 KB per block.
struct SC32 { f32x2 dt; unsigned int xc, sz; f32x4 B0, B1, C0, C1; };

template <int FULL>
__global__ __launch_bounds__(64) void scan_seg(
    const float* __restrict__ dtT, const unsigned short* __restrict__ xcT,
    const float* __restrict__ BCt, const unsigned short* __restrict__ szT,
    const float* __restrict__ A_log, const float* __restrict__ Dp,
    const float* __restrict__ HIN, float* __restrict__ P, float* __restrict__ HL,
    unsigned short* __restrict__ ybf) {
  __shared__ float dtS[4 * 36];
  __shared__ float dtxS[4 * 36];
  __shared__ float BS[16 * 36];
  __shared__ float CS[FULL ? 16 * 36 : 1];
  __shared__ unsigned int xcR[FULL ? 4 * 18 : 1];
  __shared__ unsigned int szR[FULL ? 4 * 18 : 1];
  __shared__ float ysh[FULL ? 16 * 36 : 1];
  const int lane = threadIdx.x;
  const int s = lane & 15, dl = lane >> 4;
  const int d0 = blockIdx.x * 4;
  const int d = d0 + dl;
  const int b = blockIdx.y;
  const int seg = blockIdx.z;
  const int lseg = seg * SEGL;
  const size_t rbase = (size_t)b * L_SEQ + lseg;
  const float a2 = -fexp(A_log[d * 16 + s]) * 1.44269504f;
  const float dpv = Dp[d];
  const float* dtbase = dtT + (size_t)d0 * M_ROWS + rbase;
  const unsigned short* xcbase = xcT + (size_t)d0 * M_ROWS + rbase;
  const unsigned short* szbase = szT + (size_t)d0 * M_ROWS + rbase;
  const float* Bbase = BCt + (size_t)b * 32 * L_SEQ + lseg;
  const float* Cbase = Bbase + 16 * L_SEQ;
  const int ch = lane >> 4, li = lane & 15;     // dt/xc/sz staging map
  const int s4 = lane >> 2, lj = lane & 3;      // B/C staging map
  float* ywp = &ysh[(dl * 4 + (s >> 2)) * 36 + (s & 3)];
  const bool sb0 = (s & 1) != 0, sb1 = (s & 2) != 0;
  float h = 0.f, sdt = 0.f;
  size_t o = (((size_t)seg * B_SZ + b) * DINNER + d) * 16 + s;
  if (FULL) h = HIN[o];

  auto load32 = [&](SC32& R, int l0) {
    R.dt = *(const f32x2*)(dtbase + (size_t)ch * M_ROWS + l0 + li * 2);
    R.xc = *(const unsigned int*)(xcbase + (size_t)ch * M_ROWS + l0 + li * 2);
    if (FULL) R.sz = *(const unsigned int*)(szbase + (size_t)ch * M_ROWS + l0 + li * 2);
    R.B0 = *(const f32x4*)(Bbase + (size_t)s4 * L_SEQ + l0 + lj * 8);
    R.B1 = *(const f32x4*)(Bbase + (size_t)s4 * L_SEQ + l0 + lj * 8 + 4);
    if (FULL) {
      R.C0 = *(const f32x4*)(Cbase + (size_t)s4 * L_SEQ + l0 + lj * 8);
      R.C1 = *(const f32x4*)(Cbase + (size_t)s4 * L_SEQ + l0 + lj * 8 + 4);
    }
  };
  auto store32 = [&](const SC32& R) {
    if (!FULL) sdt += R.dt[0] + R.dt[1];
    f32x2 xf, dtx;
    xf[0] = __uint_as_float(R.xc << 16);
    xf[1] = __uint_as_float(R.xc & 0xFFFF0000u);
    dtx = R.dt * xf;
    *(f32x2*)&dtS[ch * 36 + li * 2] = R.dt;
    *(f32x2*)&dtxS[ch * 36 + li * 2] = dtx;
    if (FULL) {
      xcR[ch * 18 + li] = R.xc;
      szR[ch * 18 + li] = R.sz;
    }
    *(f32x4*)&BS[s4 * 36 + lj * 8] = R.B0;
    *(f32x4*)&BS[s4 * 36 + lj * 8 + 4] = R.B1;
    if (FULL) {
      *(f32x4*)&CS[s4 * 36 + lj * 8] = R.C0;
      *(f32x4*)&CS[s4 * 36 + lj * 8 + 4] = R.C1;
    }
  };

#pragma unroll 1
  for (int c = 0; c < NSC; c++) {
    SC32 R;
    load32(R, c * SCL);
    store32(R);
#pragma unroll
    for (int g = 0; g < 4; g++) {
      const int l0g = g * 8;
      f32x4 dta = *(const f32x4*)&dtS[dl * 36 + l0g];
      f32x4 dtb = *(const f32x4*)&dtS[dl * 36 + l0g + 4];
      f32x4 xa  = *(const f32x4*)&dtxS[dl * 36 + l0g];
      f32x4 xb  = *(const f32x4*)&dtxS[dl * 36 + l0g + 4];
      f32x4 Ba  = *(const f32x4*)&BS[s * 36 + l0g];
      f32x4 Bb  = *(const f32x4*)&BS[s * 36 + l0g + 4];
      f32x4 Ca, Cb;
      if (FULL) {
        Ca = *(const f32x4*)&CS[s * 36 + l0g];
        Cb = *(const f32x4*)&CS[s * 36 + l0g + 4];
      }
      float p8[8];
#pragma unroll
      for (int j = 0; j < 8; j++) {
        float dtj = (j < 4) ? dta[j] : dtb[j - 4];
        float dxj = (j < 4) ? xa[j]  : xb[j - 4];
        float Bj  = (j < 4) ? Ba[j]  : Bb[j - 4];
        float a = __builtin_amdgcn_exp2f(dtj * a2);
        h = a * h + dxj * Bj;
        if (FULL) {
          float Cj = (j < 4) ? Ca[j] : Cb[j - 4];
          p8[j] = h * Cj;
        }
      }
      if (FULL) {
#pragma unroll
        for (int half = 0; half < 2; half++) {
          float q0 = quad_sum(p8[half * 4 + 0]);
          float q1 = quad_sum(p8[half * 4 + 1]);
          float q2 = quad_sum(p8[half * 4 + 2]);
          float q3 = quad_sum(p8[half * 4 + 3]);
          float v01 = sb0 ? q1 : q0;
          float v23 = sb0 ? q3 : q2;
          ywp[g * 8 + half * 4] = sb1 ? v23 : v01;
        }
      }
    }
    if (FULL) {
      f32x2 y0 = *(const f32x2*)&ysh[(dl * 4 + 0) * 36 + s * 2];
      f32x2 y1 = *(const f32x2*)&ysh[(dl * 4 + 1) * 36 + s * 2];
      f32x2 y2 = *(const f32x2*)&ysh[(dl * 4 + 2) * 36 + s * 2];
      f32x2 y3 = *(const f32x2*)&ysh[(dl * 4 + 3) * 36 + s * 2];
      f32x2 ys = y0 + y1 + y2 + y3;
      unsigned int xcu = xcR[dl * 18 + s];
      unsigned int szu = szR[dl * 18 + s];
      float xcf[2] = {__uint_as_float(xcu << 16), __uint_as_float(xcu & 0xFFFF0000u)};
      float szf[2] = {__uint_as_float(szu << 16), __uint_as_float(szu & 0xFFFF0000u)};
      size_t rr0 = rbase + c * SCL + s * 2;
#pragma unroll
      for (int i = 0; i < 2; i++) {
        float yv = ys[i] + xcf[i] * dpv;
        ybf[(rr0 + i) * DINNER + d] = f2bf(yv * szf[i]);
      }
    }
  }
  if (!FULL) {
    sdt = row16_sum(sdt);
    P[o] = __builtin_amdgcn_exp2f(a2 * sdt);
    HL[o] = h;
  }
}

__global__ void scan_comb(const float* __restrict__ P, const float* __restrict__ HL,
                          float* __restrict__ HIN) {
  int tg = blockIdx.x * 256 + threadIdx.x;  // 49152
  int s = tg & 15;
  int rem = tg >> 4;
  int d = rem % DINNER;
  int b = rem / DINNER;
  float h = 0.f;
  for (int g = 0; g < NSEG; g++) {
    size_t o = (((size_t)g * B_SZ + b) * DINNER + d) * 16 + s;
    HIN[o] = h;
    if (g < NSEG - 1) h = P[o] * h + HL[o];
  }
}

// -------------------------------------------------------------- launcher ----
extern "C" void kernel_launch(void* const* d_in, const int* in_sizes, int n_in,
                              void* d_out, int out_size, void* d_ws, size_t ws_size,
                              hipStream_t stream) {
  const float* x    = (const float*)d_in[0];
  const float* w1   = (const float*)d_in[1];
  const float* cw   = (const float*)d_in[2];
  const float* cb   = (const float*)d_in[3];
  const float* alog = (const float*)d_in[4];
  const float* Dp   = (const float*)d_in[5];
  const float* w2   = (const float*)d_in[6];
  const float* dtw  = (const float*)d_in[7];
  const float* dtb  = (const float*)d_in[8];
  const float* w3   = (const float*)d_in[9];
  float* out = (float*)d_out;
  char* ws = (char*)d_ws;

  size_t off = 0;
  auto alloc = [&](size_t bytes) { size_t o = off; off += (bytes + 255) & ~(size_t)255; return o; };
  // xz region reused: after conv + szT consume it, dtT and ybf overlay it.
  char*           xzr   = ws + alloc((size_t)M_ROWS * 3072 * 4);
  float*          xz    = (float*)xzr;
  float*          dtT   = (float*)xzr;                                          // [1536][4096] f32
  unsigned short* ybf   = (unsigned short*)(xzr + (size_t)DINNER * M_ROWS * 4); // [4096][1536] bf16
  float*          xdblS = (float*)(ws + alloc((size_t)KSPLIT * M_ROWS * 128 * 4)); // 8 slabs
  unsigned short* xbf   = (unsigned short*)(ws + alloc((size_t)M_ROWS * DMODEL * 2));
  unsigned short* w1bf  = (unsigned short*)(ws + alloc((size_t)2 * DINNER * DMODEL * 2));
  unsigned short* w2bf  = (unsigned short*)(ws + alloc((size_t)128 * DINNER * 2));
  unsigned short* w3bf  = (unsigned short*)(ws + alloc((size_t)DMODEL * DINNER * 2));
  unsigned short* dtlbf = (unsigned short*)(ws + alloc((size_t)M_ROWS * 64 * 2));
  unsigned short* dtwbf = (unsigned short*)(ws + alloc((size_t)DINNER * 64 * 2));
  unsigned short* xcbf  = (unsigned short*)(ws + alloc((size_t)M_ROWS * DINNER * 2));
  unsigned short* xcT   = (unsigned short*)(ws + alloc((size_t)DINNER * M_ROWS * 2));
  unsigned short* szbf  = (unsigned short*)(ws + alloc((size_t)DINNER * M_ROWS * 2));
  float*          BCt   = (float*)(ws + alloc((size_t)B_SZ * 32 * L_SEQ * 4));
  float*          Pbuf  = (float*)(ws + alloc((size_t)NSEG * B_SZ * DINNER * 16 * 4));
  float*          HLbuf = (float*)(ws + alloc((size_t)NSEG * B_SZ * DINNER * 16 * 4));
  float*          HINb  = (float*)(ws + alloc((size_t)NSEG * B_SZ * DINNER * 16 * 4));

  // 1. casts
  cast_all_kernel<<<27264, 256, 0, stream>>>(x, w1, w2, w3, dtw, xbf, w1bf, w2bf, w3bf, dtwbf);
  // 2. xz = x @ W_in^T
  gemm_bt<0><<<dim3(32, 24), 256, 0, stream>>>(xbf, w1bf, xz, DMODEL, DMODEL, 3072, 0, nullptr);
  // 3. conv+SiLU -> xcbf (row) + xcT (transposed), fused
  conv_silu_t<<<dim3(64, 24), 256, 0, stream>>>(xz, cw, cb, xcbf, xcT);
  // 4. szT = silu(z)^T
  transpose_silu<<<dim3(64, 24), 256, 0, stream>>>(xz, szbf);
  // 5. x_dbl slabs = xc @ W_x^T, split-K x8 with private slabs (no atomics)
  gemm_bt<0><<<dim3(32, 1, KSPLIT), 256, 0, stream>>>(xcbf, w2bf, xdblS, DINNER,
                                                      DINNER / KSPLIT, 128,
                                                      (long)M_ROWS * 128, nullptr);
  // 6. slab-reduce + dt_low cast + B/C transpose (merged)
  xdbl_pack_kernel<<<1152, 256, 0, stream>>>(xdblS, dtlbf, BCt);
  // 7. dtT = softplus(W_dt @ dt_low^T + b)  [1536][4096], overlays xz
  gemm_bt<2><<<dim3(12, 32), 256, 0, stream>>>(dtwbf, dtlbf, dtT, 64, 64, M_ROWS, 0, dtb);
  // 8-10. segmented scan (NSEG=8)
  scan_seg<0><<<dim3(384, 2, NSEG - 1), 64, 0, stream>>>(dtT, xcT, BCt, szbf, alog, Dp,
                                                         nullptr, Pbuf, HLbuf, nullptr);
  scan_comb<<<192, 256, 0, stream>>>(Pbuf, HLbuf, HINb);
  scan_seg<1><<<dim3(384, 2, NSEG), 64, 0, stream>>>(dtT, xcT, BCt, szbf, alog, Dp,
                                                     HINb, nullptr, nullptr, ybf);
  // 11. out = y @ W_out^T
  gemm_bt<0><<<dim3(32, 6), 256, 0, stream>>>(ybf, w3bf, out, DINNER, DINNER, 768, 0, nullptr);
}

// Round 9
// 295.235 us; speedup vs baseline: 1.3783x; 1.0317x over previous
//
#include <hip/hip_runtime.h>
#include <stdint.h>

#define B_SZ    2
#define L_SEQ   2048
#define DMODEL  768
#define DSTATE  16
#define DINNER  1536
#define DTRANK  48
#define M_ROWS  4096      // B*L
#define NSEG    8
#define SEGL    256
#define NSC     8         // superchunks per segment
#define SCL     32        // steps per superchunk
#define KSPLIT  8         // gemm2 split-K slabs

typedef __attribute__((ext_vector_type(8))) short bf16x8;
typedef __attribute__((ext_vector_type(4))) float f32x4;
typedef __attribute__((ext_vector_type(2))) float f32x2;
typedef __attribute__((ext_vector_type(4))) unsigned int u32x4;
typedef __attribute__((ext_vector_type(2))) unsigned int u32x2;

__device__ __forceinline__ unsigned short f2bf(float f) {
  unsigned int u = __float_as_uint(f);
  u += 0x7FFFu + ((u >> 16) & 1u);          // RNE
  return (unsigned short)(u >> 16);
}
__device__ __forceinline__ unsigned int pack2bf(float a, float b) {
  return (unsigned int)f2bf(a) | ((unsigned int)f2bf(b) << 16);
}
__device__ __forceinline__ float fexp(float x) {
  return __builtin_amdgcn_exp2f(x * 1.44269504088896340736f);
}
__device__ __forceinline__ float sigm(float x) {
  return 1.0f / (1.0f + fexp(-x));
}

template <int CTRL>
__device__ __forceinline__ float dpp_add(float v) {
  int x = __builtin_amdgcn_update_dpp(0, __float_as_int(v), CTRL, 0xF, 0xF, true);
  return v + __int_as_float(x);
}
__device__ __forceinline__ float quad_sum(float v) {
  v = dpp_add<0xB1>(v);   // quad_perm [1,0,3,2]
  v = dpp_add<0x4E>(v);   // quad_perm [2,3,0,1]
  return v;
}
__device__ __forceinline__ float row16_sum(float v) {
  v = dpp_add<0xB1>(v);
  v = dpp_add<0x4E>(v);
  v = dpp_add<0x124>(v);  // row_ror:4
  v = dpp_add<0x128>(v);  // row_ror:8
  return v;
}

// async global->LDS, 16B per lane; LDS dest is wave-uniform base + lane*16
__device__ __forceinline__ void gload_lds(const unsigned short* g, unsigned short* l) {
  __builtin_amdgcn_global_load_lds((__attribute__((address_space(1))) void*)g,
                                   (__attribute__((address_space(3))) void*)l, 16, 0, 0);
}

// ---------------------------------------------------------------- casts ----
__global__ void cast_all_kernel(const float* __restrict__ x, const float* __restrict__ w1,
                                const float* __restrict__ w2, const float* __restrict__ w3,
                                const float* __restrict__ dtw,
                                unsigned short* __restrict__ xbf, unsigned short* __restrict__ w1bf,
                                unsigned short* __restrict__ w2bf, unsigned short* __restrict__ w3bf,
                                unsigned short* __restrict__ dtwbf) {
  int i = blockIdx.x * 256 + threadIdx.x;
  const int n_x = M_ROWS * DMODEL;
  const int n_w1 = 2 * DINNER * DMODEL;
  const int n_w3 = DMODEL * DINNER;
  const int n_w2 = 128 * DINNER;
  const int n_dtw = DINNER * 64;
  if (i < n_x)  { xbf[i] = f2bf(x[i]); return; }  i -= n_x;
  if (i < n_w1) { w1bf[i] = f2bf(w1[i]); return; } i -= n_w1;
  if (i < n_w3) { w3bf[i] = f2bf(w3[i]); return; } i -= n_w3;
  if (i < n_w2) {
    int row = i / DINNER, col = i - row * DINNER;
    w2bf[i] = (row < (DTRANK + 2 * DSTATE)) ? f2bf(w2[row * DINNER + col]) : (unsigned short)0;
    return;
  }
  i -= n_w2;
  if (i < n_dtw) {
    int row = i >> 6, col = i & 63;
    dtwbf[i] = (col < DTRANK) ? f2bf(dtw[row * DTRANK + col]) : (unsigned short)0;
  }
}

// merged: reduce 8 gemm2 slabs + cast dt_low (padded K=64) + B/C transpose
__global__ void xdbl_pack_kernel(const float* __restrict__ xdblS,
                                 unsigned short* __restrict__ dtlbf,
                                 float* __restrict__ BCt) {
  const int SLAB = M_ROWS * 128;
  int i = blockIdx.x * 256 + threadIdx.x;
  const int n_dtl = M_ROWS * 64;            // 262144
  if (i < n_dtl) {
    int row = i >> 6, col = i & 63;
    if (col < DTRANK) {
      float v = 0.f;
#pragma unroll
      for (int z = 0; z < KSPLIT; z++) v += xdblS[(size_t)z * SLAB + row * 128 + col];
      dtlbf[i] = f2bf(v);
    } else dtlbf[i] = 0;
    return;
  }
  i -= n_dtl;                               // 32768 entries
  int l4 = i & 511;
  int j  = (i >> 9) & 31;
  int b  = (i >> 14) & 1;
  f32x4 o;
#pragma unroll
  for (int k = 0; k < 4; k++) {
    float v = 0.f;
    size_t base = ((size_t)b * L_SEQ + l4 * 4 + k) * 128 + DTRANK + j;
#pragma unroll
    for (int z = 0; z < KSPLIT; z++) v += xdblS[(size_t)z * SLAB + base];
    o[k] = v;
  }
  *(f32x4*)(BCt + ((size_t)b * 32 + j) * L_SEQ + l4 * 4) = o;
}

// ------------------------------- async bf16 MFMA GEMM (B^T), m97 structure ----
// C[z*slab + m*ldc + n] = sum_{k in slice} A[m][k]*Bt[n][k]. Unpadded LDS
// 128x32 tiles filled by global_load_lds width=16; 2-barrier K-loop.
__global__ __launch_bounds__(256, 2) void gemm_async(
    const unsigned short* __restrict__ A, const unsigned short* __restrict__ Bt,
    float* __restrict__ C, int K, int KS, int ldc, long slab) {
  __shared__ unsigned short As[128 * 32];
  __shared__ unsigned short Bs[128 * 32];
  const int tid = threadIdx.x;
  const int lane = tid & 63;
  const int wv = tid >> 6;
  const int m0 = blockIdx.x * 128;
  const int n0 = blockIdx.y * 128;
  const int ks = blockIdx.z * KS, ke = ks + KS;
  float* Cz = C + (size_t)blockIdx.z * slab;
  const int wr = (wv >> 1) * 64, wc = (wv & 1) * 64;
  const int lm = lane & 15, q = lane >> 4;
  const int srow = wv * 16 + (lane >> 2);   // staging row within 64-row half
  const int scol = (lane & 3) * 8;          // staging col (elems)

  f32x4 acc[4][4] = {};

  for (int k0 = ks; k0 < ke; k0 += 32) {
#pragma unroll
    for (int j = 0; j < 2; j++) {
      gload_lds(A + (size_t)(m0 + j * 64 + srow) * K + k0 + scol, &As[(j * 64 + wv * 16) * 32]);
      gload_lds(Bt + (size_t)(n0 + j * 64 + srow) * K + k0 + scol, &Bs[(j * 64 + wv * 16) * 32]);
    }
    __syncthreads();                       // compiler drains vmcnt before barrier
    bf16x8 af[4], bq[4];
#pragma unroll
    for (int mt = 0; mt < 4; mt++)
      af[mt] = *(const bf16x8*)&As[(wr + mt * 16 + lm) * 32 + q * 8];
#pragma unroll
    for (int nt = 0; nt < 4; nt++)
      bq[nt] = *(const bf16x8*)&Bs[(wc + nt * 16 + lm) * 32 + q * 8];
#pragma unroll
    for (int mt = 0; mt < 4; mt++)
#pragma unroll
      for (int nt = 0; nt < 4; nt++)
        acc[mt][nt] = __builtin_amdgcn_mfma_f32_16x16x32_bf16(af[mt], bq[nt], acc[mt][nt], 0, 0, 0);
    __syncthreads();
  }

#pragma unroll
  for (int mt = 0; mt < 4; mt++) {
    int row0 = m0 + wr + mt * 16 + q * 4;
#pragma unroll
    for (int nt = 0; nt < 4; nt++) {
      int col = n0 + wc + nt * 16 + lm;
#pragma unroll
      for (int i = 0; i < 4; i++)
        Cz[(size_t)(row0 + i) * ldc + col] = acc[mt][nt][i];
    }
  }
}

// --------------------- padded VGPR-staging GEMM, kept for the dt projection ----
// EPI=2: softplus(acc + bias[row]).
__global__ __launch_bounds__(256, 2) void gemm_dt(
    const unsigned short* __restrict__ A, const unsigned short* __restrict__ Bt,
    float* __restrict__ C, int K, int ldc, const float* __restrict__ bias) {
  __shared__ unsigned short As[128 * 40];
  __shared__ unsigned short Bs[128 * 40];
  const int tid = threadIdx.x;
  const int m0 = blockIdx.x * 128;
  const int n0 = blockIdx.y * 128;
  const int lane = tid & 63;
  const int wave = tid >> 6;
  const int wr = (wave >> 1) * 64, wc = (wave & 1) * 64;
  const int lm = lane & 15, q = lane >> 4;
  const int r = tid >> 2, sg = (tid & 3) * 8;

  f32x4 acc[4][4] = {};

  for (int k0 = 0; k0 < K; k0 += 32) {
    u32x4 a0 = *(const u32x4*)(A + (size_t)(m0 + r) * K + k0 + sg);
    u32x4 a1 = *(const u32x4*)(A + (size_t)(m0 + r + 64) * K + k0 + sg);
    u32x4 b0 = *(const u32x4*)(Bt + (size_t)(n0 + r) * K + k0 + sg);
    u32x4 b1 = *(const u32x4*)(Bt + (size_t)(n0 + r + 64) * K + k0 + sg);
    __syncthreads();
    *(u32x4*)&As[r * 40 + sg] = a0;
    *(u32x4*)&As[(r + 64) * 40 + sg] = a1;
    *(u32x4*)&Bs[r * 40 + sg] = b0;
    *(u32x4*)&Bs[(r + 64) * 40 + sg] = b1;
    __syncthreads();
    bf16x8 af[4], bq[4];
#pragma unroll
    for (int mt = 0; mt < 4; mt++)
      af[mt] = *(const bf16x8*)&As[(wr + mt * 16 + lm) * 40 + q * 8];
#pragma unroll
    for (int nt = 0; nt < 4; nt++)
      bq[nt] = *(const bf16x8*)&Bs[(wc + nt * 16 + lm) * 40 + q * 8];
#pragma unroll
    for (int mt = 0; mt < 4; mt++)
#pragma unroll
      for (int nt = 0; nt < 4; nt++)
        acc[mt][nt] = __builtin_amdgcn_mfma_f32_16x16x32_bf16(af[mt], bq[nt], acc[mt][nt], 0, 0, 0);
  }

#pragma unroll
  for (int mt = 0; mt < 4; mt++) {
    int row0 = m0 + wr + mt * 16 + q * 4;
    float bs4[4];
#pragma unroll
    for (int i = 0; i < 4; i++) bs4[i] = bias[row0 + i];
#pragma unroll
    for (int nt = 0; nt < 4; nt++) {
      int col = n0 + wc + nt * 16 + lm;
#pragma unroll
      for (int i = 0; i < 4; i++) {
        float v = acc[mt][nt][i] + bs4[i];
        v = (v > 15.f) ? v : log1pf(fexp(v));
        C[(size_t)(row0 + i) * ldc + col] = v;
      }
    }
  }
}

// ---- fused depthwise conv+SiLU -> xcbf + xcT, then z-half SiLU -> szT ------
__global__ __launch_bounds__(256) void conv_silu_zt(const float* __restrict__ xz,
                                                    const float* __restrict__ cw,
                                                    const float* __restrict__ cb,
                                                    unsigned short* __restrict__ xcbf,
                                                    unsigned short* __restrict__ xcT,
                                                    unsigned short* __restrict__ szT) {
  __shared__ float tl[67 * 68];
  __shared__ unsigned short xs[64 * 80];
  __shared__ float cws[256];
  __shared__ float cbs[64];
  const int r0 = blockIdx.x * 64;     // global row b*L+l
  const int c0 = blockIdx.y * 64;     // channel d
  const int t = threadIdx.x;
  cws[t] = cw[(c0 + (t >> 2)) * 4 + (t & 3)];
  if (t < 64) cbs[t] = cb[c0 + t];
  const bool lowedge = (r0 & (L_SEQ - 1)) == 0;
  // phase A: conv input tile (rows -3..63)
#pragma unroll
  for (int it = 0; it < 5; it++) {
    int idx = t + it * 256;
    int rr = idx >> 4;
    int cs4 = (idx & 15) * 4;
    if (rr < 67) {
      f32x4 v;
      if (lowedge && rr < 3) v = (f32x4){0.f, 0.f, 0.f, 0.f};
      else v = *(const f32x4*)(xz + (size_t)(r0 + rr - 3) * 3072 + c0 + cs4);
      *(f32x4*)&tl[rr * 68 + cs4] = v;
    }
  }
  __syncthreads();
  {
    const int cs = (t & 15) * 4;
    f32x4 w0, w1, w2, w3, cbv;
#pragma unroll
    for (int j = 0; j < 4; j++) {
      w0[j] = cws[(cs + j) * 4 + 0];
      w1[j] = cws[(cs + j) * 4 + 1];
      w2[j] = cws[(cs + j) * 4 + 2];
      w3[j] = cws[(cs + j) * 4 + 3];
      cbv[j] = cbs[cs + j];
    }
#pragma unroll
    for (int it = 0; it < 4; it++) {
      int r = (t >> 4) + it * 16;
      f32x4 t0 = *(const f32x4*)&tl[(r + 0) * 68 + cs];
      f32x4 t1 = *(const f32x4*)&tl[(r + 1) * 68 + cs];
      f32x4 t2 = *(const f32x4*)&tl[(r + 2) * 68 + cs];
      f32x4 t3 = *(const f32x4*)&tl[(r + 3) * 68 + cs];
      f32x4 acc = cbv + w0 * t0 + w1 * t1 + w2 * t2 + w3 * t3;
#pragma unroll
      for (int j = 0; j < 4; j++) acc[j] = acc[j] * sigm(acc[j]);
      u32x2 pk;
      pk[0] = pack2bf(acc[0], acc[1]);
      pk[1] = pack2bf(acc[2], acc[3]);
      *(u32x2*)(xcbf + (size_t)(r0 + r) * DINNER + c0 + cs) = pk;
      *(u32x2*)&xs[r * 80 + cs] = pk;
    }
  }
  __syncthreads();      // xs ready; tl reads done -> safe to overwrite tl with z
  // phase B: load z tile (overwrites tl) + write xcT from xs
#pragma unroll
  for (int it = 0; it < 4; it++) {
    int idx = t + it * 256;
    int rr = idx >> 4, cs = idx & 15;
    f32x4 v = *(const f32x4*)(xz + (size_t)(r0 + rr) * 3072 + DINNER + c0 + cs * 4);
#pragma unroll
    for (int p = 0; p < 4; p++) v[p] = v[p] * sigm(v[p]);
    *(f32x4*)&tl[rr * 68 + cs * 4] = v;
  }
#pragma unroll
  for (int it = 0; it < 2; it++) {
    int idx = t + it * 256;
    int cc = idx & 63, rs = idx >> 6;
    unsigned int w[4];
#pragma unroll
    for (int p = 0; p < 4; p++) {
      unsigned int lo = xs[(rs * 8 + 2 * p) * 80 + cc];
      unsigned int hi = xs[(rs * 8 + 2 * p + 1) * 80 + cc];
      w[p] = lo | (hi << 16);
    }
    *(u32x4*)(xcT + (size_t)(c0 + cc) * M_ROWS + r0 + rs * 8) = *(u32x4*)w;
  }
  __syncthreads();
  // phase C: transpose-pack z -> szT
#pragma unroll
  for (int it = 0; it < 2; it++) {
    int idx = t + it * 256;
    int cc = idx & 63, rs = idx >> 6;
    unsigned int w[4];
#pragma unroll
    for (int p = 0; p < 4; p++)
      w[p] = pack2bf(tl[(rs * 8 + 2 * p) * 68 + cc], tl[(rs * 8 + 2 * p + 1) * 68 + cc]);
    *(u32x4*)(szT + (size_t)(c0 + cc) * M_ROWS + r0 + rs * 8) = *(u32x4*)w;
  }
}

// ------------------------------------------------ segmented selective scan ----
// 256-thr block = 4 waves, each wave an independent (4-channel group, batch,
// segment) scanner with a private LDS quarter. No barriers.
struct SC32 { f32x2 dt; unsigned int xc, sz; f32x4 B0, B1, C0, C1; };

template <int FULL>
__global__ __launch_bounds__(256) void scan_seg(
    const float* __restrict__ dtT, const unsigned short* __restrict__ xcT,
    const float* __restrict__ BCt, const unsigned short* __restrict__ szT,
    const float* __restrict__ A_log, const float* __restrict__ Dp,
    const float* __restrict__ HIN, float* __restrict__ P, float* __restrict__ HL,
    unsigned short* __restrict__ ybf) {
  __shared__ float dtS[4][4 * 36];
  __shared__ float dtxS[4][4 * 36];
  __shared__ float BS[4][16 * 36];
  __shared__ float CS[FULL ? 4 : 1][FULL ? 16 * 36 : 1];
  __shared__ unsigned int xcR[FULL ? 4 : 1][FULL ? 4 * 18 : 1];
  __shared__ unsigned int szR[FULL ? 4 : 1][FULL ? 4 * 18 : 1];
  __shared__ float ysh[FULL ? 4 : 1][FULL ? 16 * 36 : 1];
  const int tid = threadIdx.x;
  const int wv = tid >> 6;
  const int lane = tid & 63;
  const int s = lane & 15, dl = lane >> 4;
  const int d0 = blockIdx.x * 16 + wv * 4;
  const int d = d0 + dl;
  const int b = blockIdx.y;
  const int seg = blockIdx.z;
  const int lseg = seg * SEGL;
  const size_t rbase = (size_t)b * L_SEQ + lseg;
  const float a2 = -fexp(A_log[d * 16 + s]) * 1.44269504f;
  const float dpv = Dp[d];
  const float* dtbase = dtT + (size_t)d0 * M_ROWS + rbase;
  const unsigned short* xcbase = xcT + (size_t)d0 * M_ROWS + rbase;
  const unsigned short* szbase = szT + (size_t)d0 * M_ROWS + rbase;
  const float* Bbase = BCt + (size_t)b * 32 * L_SEQ + lseg;
  const float* Cbase = Bbase + 16 * L_SEQ;
  const int ch = lane >> 4, li = lane & 15;     // dt/xc/sz staging map
  const int s4 = lane >> 2, lj = lane & 3;      // B/C staging map
  float* dtSw = dtS[wv];
  float* dtxSw = dtxS[wv];
  float* BSw = BS[wv];
  float* CSw = FULL ? CS[wv] : nullptr;
  float* ywp = FULL ? &ysh[wv][(dl * 4 + (s >> 2)) * 36 + (s & 3)] : nullptr;
  const bool sb0 = (s & 1) != 0, sb1 = (s & 2) != 0;
  float h = 0.f, sdt = 0.f;
  size_t o = (((size_t)seg * B_SZ + b) * DINNER + d) * 16 + s;
  if (FULL) h = HIN[o];

  auto load32 = [&](SC32& R, int l0) {
    R.dt = *(const f32x2*)(dtbase + (size_t)ch * M_ROWS + l0 + li * 2);
    R.xc = *(const unsigned int*)(xcbase + (size_t)ch * M_ROWS + l0 + li * 2);
    if (FULL) R.sz = *(const unsigned int*)(szbase + (size_t)ch * M_ROWS + l0 + li * 2);
    R.B0 = *(const f32x4*)(Bbase + (size_t)s4 * L_SEQ + l0 + lj * 8);
    R.B1 = *(const f32x4*)(Bbase + (size_t)s4 * L_SEQ + l0 + lj * 8 + 4);
    if (FULL) {
      R.C0 = *(const f32x4*)(Cbase + (size_t)s4 * L_SEQ + l0 + lj * 8);
      R.C1 = *(const f32x4*)(Cbase + (size_t)s4 * L_SEQ + l0 + lj * 8 + 4);
    }
  };
  auto store32 = [&](const SC32& R) {
    if (!FULL) sdt += R.dt[0] + R.dt[1];
    f32x2 xf, dtx;
    xf[0] = __uint_as_float(R.xc << 16);
    xf[1] = __uint_as_float(R.xc & 0xFFFF0000u);
    dtx = R.dt * xf;
    *(f32x2*)&dtSw[ch * 36 + li * 2] = R.dt;
    *(f32x2*)&dtxSw[ch * 36 + li * 2] = dtx;
    if (FULL) {
      xcR[wv][ch * 18 + li] = R.xc;
      szR[wv][ch * 18 + li] = R.sz;
    }
    *(f32x4*)&BSw[s4 * 36 + lj * 8] = R.B0;
    *(f32x4*)&BSw[s4 * 36 + lj * 8 + 4] = R.B1;
    if (FULL) {
      *(f32x4*)&CSw[s4 * 36 + lj * 8] = R.C0;
      *(f32x4*)&CSw[s4 * 36 + lj * 8 + 4] = R.C1;
    }
  };

#pragma unroll 1
  for (int c = 0; c < NSC; c++) {
    SC32 R;
    load32(R, c * SCL);
    store32(R);
#pragma unroll
    for (int g = 0; g < 4; g++) {
      const int l0g = g * 8;
      f32x4 dta = *(const f32x4*)&dtSw[dl * 36 + l0g];
      f32x4 dtb = *(const f32x4*)&dtSw[dl * 36 + l0g + 4];
      f32x4 xa  = *(const f32x4*)&dtxSw[dl * 36 + l0g];
      f32x4 xb  = *(const f32x4*)&dtxSw[dl * 36 + l0g + 4];
      f32x4 Ba  = *(const f32x4*)&BSw[s * 36 + l0g];
      f32x4 Bb  = *(const f32x4*)&BSw[s * 36 + l0g + 4];
      f32x4 Ca, Cb;
      if (FULL) {
        Ca = *(const f32x4*)&CSw[s * 36 + l0g];
        Cb = *(const f32x4*)&CSw[s * 36 + l0g + 4];
      }
      float p8[8];
#pragma unroll
      for (int j = 0; j < 8; j++) {
        float dtj = (j < 4) ? dta[j] : dtb[j - 4];
        float dxj = (j < 4) ? xa[j]  : xb[j - 4];
        float Bj  = (j < 4) ? Ba[j]  : Bb[j - 4];
        float a = __builtin_amdgcn_exp2f(dtj * a2);
        h = a * h + dxj * Bj;
        if (FULL) {
          float Cj = (j < 4) ? Ca[j] : Cb[j - 4];
          p8[j] = h * Cj;
        }
      }
      if (FULL) {
#pragma unroll
        for (int half = 0; half < 2; half++) {
          float q0 = quad_sum(p8[half * 4 + 0]);
          float q1 = quad_sum(p8[half * 4 + 1]);
          float q2 = quad_sum(p8[half * 4 + 2]);
          float q3 = quad_sum(p8[half * 4 + 3]);
          float v01 = sb0 ? q1 : q0;
          float v23 = sb0 ? q3 : q2;
          ywp[g * 8 + half * 4] = sb1 ? v23 : v01;
        }
      }
    }
    if (FULL) {
      f32x2 y0 = *(const f32x2*)&ysh[wv][(dl * 4 + 0) * 36 + s * 2];
      f32x2 y1 = *(const f32x2*)&ysh[wv][(dl * 4 + 1) * 36 + s * 2];
      f32x2 y2 = *(const f32x2*)&ysh[wv][(dl * 4 + 2) * 36 + s * 2];
      f32x2 y3 = *(const f32x2*)&ysh[wv][(dl * 4 + 3) * 36 + s * 2];
      f32x2 ys = y0 + y1 + y2 + y3;
      unsigned int xcu = xcR[wv][dl * 18 + s];
      unsigned int szu = szR[wv][dl * 18 + s];
      float xcf[2] = {__uint_as_float(xcu << 16), __uint_as_float(xcu & 0xFFFF0000u)};
      float szf[2] = {__uint_as_float(szu << 16), __uint_as_float(szu & 0xFFFF0000u)};
      size_t rr0 = rbase + c * SCL + s * 2;
#pragma unroll
      for (int i = 0; i < 2; i++) {
        float yv = ys[i] + xcf[i] * dpv;
        ybf[(rr0 + i) * DINNER + d] = f2bf(yv * szf[i]);
      }
    }
  }
  if (!FULL) {
    sdt = row16_sum(sdt);
    P[o] = __builtin_amdgcn_exp2f(a2 * sdt);
    HL[o] = h;
  }
}

__global__ void scan_comb(const float* __restrict__ P, const float* __restrict__ HL,
                          float* __restrict__ HIN) {
  int tg = blockIdx.x * 256 + threadIdx.x;  // 49152
  int s = tg & 15;
  int rem = tg >> 4;
  int d = rem % DINNER;
  int b = rem / DINNER;
  float h = 0.f;
  for (int g = 0; g < NSEG; g++) {
    size_t o = (((size_t)g * B_SZ + b) * DINNER + d) * 16 + s;
    HIN[o] = h;
    if (g < NSEG - 1) h = P[o] * h + HL[o];
  }
}

// -------------------------------------------------------------- launcher ----
extern "C" void kernel_launch(void* const* d_in, const int* in_sizes, int n_in,
                              void* d_out, int out_size, void* d_ws, size_t ws_size,
                              hipStream_t stream) {
  const float* x    = (const float*)d_in[0];
  const float* w1   = (const float*)d_in[1];
  const float* cw   = (const float*)d_in[2];
  const float* cb   = (const float*)d_in[3];
  const float* alog = (const float*)d_in[4];
  const float* Dp   = (const float*)d_in[5];
  const float* w2   = (const float*)d_in[6];
  const float* dtw  = (const float*)d_in[7];
  const float* dtb  = (const float*)d_in[8];
  const float* w3   = (const float*)d_in[9];
  float* out = (float*)d_out;
  char* ws = (char*)d_ws;

  size_t off = 0;
  auto alloc = [&](size_t bytes) { size_t o = off; off += (bytes + 255) & ~(size_t)255; return o; };
  // xz region reused: after conv+szT consume it, dtT and ybf overlay it.
  char*           xzr   = ws + alloc((size_t)M_ROWS * 3072 * 4);
  float*          xz    = (float*)xzr;
  float*          dtT   = (float*)xzr;                                          // [1536][4096] f32
  unsigned short* ybf   = (unsigned short*)(xzr + (size_t)DINNER * M_ROWS * 4); // [4096][1536] bf16
  float*          xdblS = (float*)(ws + alloc((size_t)KSPLIT * M_ROWS * 128 * 4)); // 8 slabs
  unsigned short* xbf   = (unsigned short*)(ws + alloc((size_t)M_ROWS * DMODEL * 2));
  unsigned short* w1bf  = (unsigned short*)(ws + alloc((size_t)2 * DINNER * DMODEL * 2));
  unsigned short* w2bf  = (unsigned short*)(ws + alloc((size_t)128 * DINNER * 2));
  unsigned short* w3bf  = (unsigned short*)(ws + alloc((size_t)DMODEL * DINNER * 2));
  unsigned short* dtlbf = (unsigned short*)(ws + alloc((size_t)M_ROWS * 64 * 2));
  unsigned short* dtwbf = (unsigned short*)(ws + alloc((size_t)DINNER * 64 * 2));
  unsigned short* xcbf  = (unsigned short*)(ws + alloc((size_t)M_ROWS * DINNER * 2));
  unsigned short* xcT   = (unsigned short*)(ws + alloc((size_t)DINNER * M_ROWS * 2));
  unsigned short* szbf  = (unsigned short*)(ws + alloc((size_t)DINNER * M_ROWS * 2));
  float*          BCt   = (float*)(ws + alloc((size_t)B_SZ * 32 * L_SEQ * 4));
  float*          Pbuf  = (float*)(ws + alloc((size_t)NSEG * B_SZ * DINNER * 16 * 4));
  float*          HLbuf = (float*)(ws + alloc((size_t)NSEG * B_SZ * DINNER * 16 * 4));
  float*          HINb  = (float*)(ws + alloc((size_t)NSEG * B_SZ * DINNER * 16 * 4));

  // 1. casts
  cast_all_kernel<<<27264, 256, 0, stream>>>(x, w1, w2, w3, dtw, xbf, w1bf, w2bf, w3bf, dtwbf);
  // 2. xz = x @ W_in^T  (async staging GEMM)
  gemm_async<<<dim3(32, 24), 256, 0, stream>>>(xbf, w1bf, xz, DMODEL, DMODEL, 3072, 0);
  // 3. conv+SiLU -> xcbf/xcT, then z-SiLU -> szT (fused, one xz pass per half)
  conv_silu_zt<<<dim3(64, 24), 256, 0, stream>>>(xz, cw, cb, xcbf, xcT, szbf);
  // 4. x_dbl slabs = xc @ W_x^T, split-K x8 private slabs
  gemm_async<<<dim3(32, 1, KSPLIT), 256, 0, stream>>>(xcbf, w2bf, xdblS, DINNER,
                                                      DINNER / KSPLIT, 128,
                                                      (long)M_ROWS * 128);
  // 5. slab-reduce + dt_low cast + B/C transpose
  xdbl_pack_kernel<<<1152, 256, 0, stream>>>(xdblS, dtlbf, BCt);
  // 6. dtT = softplus(W_dt @ dt_low^T + b)  [1536][4096], overlays xz
  gemm_dt<<<dim3(12, 32), 256, 0, stream>>>(dtwbf, dtlbf, dtT, 64, M_ROWS, dtb);
  // 7-9. segmented scan (NSEG=8, 4 waves/block)
  scan_seg<0><<<dim3(96, 2, NSEG - 1), 256, 0, stream>>>(dtT, xcT, BCt, szbf, alog, Dp,
                                                         nullptr, Pbuf, HLbuf, nullptr);
  scan_comb<<<192, 256, 0, stream>>>(Pbuf, HLbuf, HINb);
  scan_seg<1><<<dim3(96, 2, NSEG), 256, 0, stream>>>(dtT, xcT, BCt, szbf, alog, Dp,
                                                     HINb, nullptr, nullptr, ybf);
  // 10. out = y @ W_out^T
  gemm_async<<<dim3(32, 6), 256, 0, stream>>>(ybf, w3bf, out, DINNER, DINNER, 768, 0);
}